// Round 6
// baseline (256.142 us; speedup 1.0000x reference)
//
#include <hip/hip_runtime.h>
#include <hip/hip_bf16.h>
#include <cstdint>

// ---------------------------------------------------------------------------
// TextBlock: BN -> {q,k,v} -> MHSA (NH=16, KD=16, D=64, N=1024) -> proj -> +res
//            -> BN -> MLP(1024, relu6) -> +res.   B=8, C=256.
// I/O FLOAT32. Intermediates bf16 for MFMA, fp32 accumulation.
// R13: XCD swizzle everywhere. R15 FAILED (forced 8 waves -> VGPR 32 + spill).
// R16 WIN: gemm3 gload_lds w16 + both-sides XOR swizzle (239.9us).
// R17 NEUTRAL: 2-phase gemm dbuf -> reverted (implicit wave overlap already
//      hides the drain at 4 blocks/CU; m99/m100 reproduced).
// R18: attn software pipeline, take 2. R14's real failure was rule #20:
//      lambdas taking short8* made the K/V arrays address-taken -> scratch
//      (VGPR stayed 64 WITH spills). Same schedule, now MACROS (textual,
//      const indices) + launch_bounds(256,2) for ~166-VGPR working set.
//      Occupancy 3 waves/SIMD (= today's effective 3.2) but loads now age
//      through a full QK+PV phase. Tripwire: VGPR>=200 or WRITE>>16MB=spill.
// ---------------------------------------------------------------------------

typedef __attribute__((ext_vector_type(8))) short short8;
typedef __attribute__((ext_vector_type(4))) float floatx4;

#define QK_SC 5.770780163555851f   // sqrt(kd)=4 times log2(e), folded into Q

__device__ __forceinline__ float b2f(unsigned short u) {
  union { unsigned int i; float f; } x; x.i = ((unsigned int)u) << 16; return x.f;
}
__device__ __forceinline__ unsigned short f2b(float f) {
  union { float f; unsigned int i; } x; x.f = f;
  unsigned int r = x.i + 0x7FFFu + ((x.i >> 16) & 1u);   // RNE
  return (unsigned short)(r >> 16);
}
// packed f32x2 -> bf16x2 (v_cvt_pk_bf16_f32 on gfx950)
__device__ __forceinline__ unsigned int f2b2(float a, float b) {
  __hip_bfloat162 h = __float22bfloat162_rn(make_float2(a, b));
  union { __hip_bfloat162 v; unsigned int u; } x; x.v = h; return x.u;
}
// async global->LDS, 16B per lane; LDS dest is wave-uniform base + lane*16.
__device__ __forceinline__ void gload16(const unsigned short* g, unsigned short* l) {
  __builtin_amdgcn_global_load_lds(
      (const __attribute__((address_space(1))) unsigned int*)g,
      (__attribute__((address_space(3))) unsigned int*)l, 16, 0, 0);
}

// ---------------------------------------------------------------------------
// prep: blocks 0..1151 convert the 6 weight mats f32->bf16 into wb;
//       blocks 1152..3199 accumulate BN1 partial sums of x into bnacc;
//       blocks 3200..3205 concat bq|bk|bv into biasqkv.
// ---------------------------------------------------------------------------
__global__ __launch_bounds__(256) void prep(
    const float* __restrict__ s0, const float* __restrict__ s1,
    const float* __restrict__ s2, const float* __restrict__ s3,
    const float* __restrict__ s4, const float* __restrict__ s5,
    unsigned short* __restrict__ dst,
    const float* __restrict__ x, float* __restrict__ acc,
    const float* __restrict__ bq, const float* __restrict__ bk,
    const float* __restrict__ bv, float* __restrict__ biasqkv) {
  int blk = blockIdx.x, t = threadIdx.x;
  if (blk < 1152) {
    int i = blk * 256 + t;   // float4-group index
    if (i >= 294912) return;
    const float* s; int li; size_t dbase;
    if (i < 16384)       { s = s0; li = i;          dbase = 0; }
    else if (i < 32768)  { s = s1; li = i - 16384;  dbase = 65536; }
    else if (i < 98304)  { s = s2; li = i - 32768;  dbase = 131072; }
    else if (i < 163840) { s = s3; li = i - 98304;  dbase = 393216; }
    else if (i < 229376) { s = s4; li = i - 163840; dbase = 655360; }
    else                 { s = s5; li = i - 229376; dbase = 917504; }
    float4 v = ((const float4*)s)[li];
    uint2 o; o.x = f2b2(v.x, v.y); o.y = f2b2(v.z, v.w);
    ((uint2*)(dst + dbase))[li] = o;
  } else if (blk < 3200) {
    int blk2 = blk - 1152;
    int b = blk2 >> 8, c = blk2 & 255;
    const float* p = x + (((size_t)(b * 256 + c)) << 10);
    float4 v = ((const float4*)p)[t];
    float s = (v.x + v.y) + (v.z + v.w);
    float s2 = (v.x * v.x + v.y * v.y) + (v.z * v.z + v.w * v.w);
    #pragma unroll
    for (int o = 32; o > 0; o >>= 1) { s += __shfl_down(s, o, 64); s2 += __shfl_down(s2, o, 64); }
    __shared__ float rs[4], rs2[4];
    int w = t >> 6;
    if ((t & 63) == 0) { rs[w] = s; rs2[w] = s2; }
    __syncthreads();
    if (t == 0) {
      atomicAdd(acc + c, (rs[0] + rs[1]) + (rs[2] + rs[3]));
      atomicAdd(acc + 256 + c, (rs2[0] + rs2[1]) + (rs2[2] + rs2[3]));
    }
  } else {
    int i = (blk - 3200) * 256 + t;   // 0..1535
    float v = (i < 256) ? bq[i] : (i < 512) ? bk[i - 256] : bv[i - 512];
    biasqkv[i] = v;
  }
}

// ---------------------------------------------------------------------------
// BN apply + transpose (finalize fused): x[b][c][n] f32 -> y_t[b][n][c] bf16.
// ---------------------------------------------------------------------------
__global__ __launch_bounds__(256) void bn_apply_t(
    const float* __restrict__ x, const float* __restrict__ acc,
    const float* __restrict__ g, const float* __restrict__ bb,
    unsigned short* __restrict__ yt) {
  int nt = blockIdx.x, ct = blockIdx.y, b = blockIdx.z;
  int t = threadIdx.x;
  __shared__ unsigned short T[64][72];
  {
    int r = t >> 2, g4 = (t & 3) * 16;
    int c = ct * 64 + r;
    float m = acc[c] * (1.0f / 8192.0f);
    float var = acc[256 + c] * (1.0f / 8192.0f) - m * m;
    float scl = g[c] * rsqrtf(var + 1e-5f);
    float shf = bb[c] - m * scl;
    const float* p = x + (((size_t)(b * 256 + c)) << 10) + nt * 64 + g4;
    float4 u0 = *(const float4*)(p);
    float4 u1 = *(const float4*)(p + 4);
    float4 u2 = *(const float4*)(p + 8);
    float4 u3 = *(const float4*)(p + 12);
    uint4 o0, o1;
    o0.x = f2b2(fmaf(u0.x, scl, shf), fmaf(u0.y, scl, shf));
    o0.y = f2b2(fmaf(u0.z, scl, shf), fmaf(u0.w, scl, shf));
    o0.z = f2b2(fmaf(u1.x, scl, shf), fmaf(u1.y, scl, shf));
    o0.w = f2b2(fmaf(u1.z, scl, shf), fmaf(u1.w, scl, shf));
    o1.x = f2b2(fmaf(u2.x, scl, shf), fmaf(u2.y, scl, shf));
    o1.y = f2b2(fmaf(u2.z, scl, shf), fmaf(u2.w, scl, shf));
    o1.z = f2b2(fmaf(u3.x, scl, shf), fmaf(u3.y, scl, shf));
    o1.w = f2b2(fmaf(u3.z, scl, shf), fmaf(u3.w, scl, shf));
    *(uint4*)&T[r][g4] = o0;
    *(uint4*)&T[r][g4 + 8] = o1;
  }
  __syncthreads();
  {
    int nr = t >> 2, cg = (t & 3) * 16;
    unsigned int ob[8];
    #pragma unroll
    for (int j = 0; j < 8; ++j) {
      unsigned int lo = T[cg + 2 * j][nr];
      unsigned int hi = T[cg + 2 * j + 1][nr];
      ob[j] = lo | (hi << 16);
    }
    unsigned short* orow = yt + ((size_t)(b * 1024 + nt * 64 + nr)) * 256 + ct * 64 + cg;
    *(uint4*)&orow[0] = make_uint4(ob[0], ob[1], ob[2], ob[3]);
    *(uint4*)&orow[8] = make_uint4(ob[4], ob[5], ob[6], ob[7]);
  }
}

// ---------------------------------------------------------------------------
// MFMA GEMM (64x64, BK=64, (256,4)):  out = W[M,K] @ Bn_b[N,K]^T + bias
// R16 staging (proven): global_load_lds w16 into UNPADDED [64][64] LDS.
//   Rule #21 both-sides swizzle: linear LDS dest, pre-swizzled global source
//   col-group (s ^ (l>>3)), read-side XOR ((q ^ (row&7))<<4).
// MODE 4: fused QKV. MODE 5: proj (+res, BN2 stats, n-major out).
// MODE 6: MLP1 (inline BN2 on B staging -> swizzled stores; relu6; n-major).
// MODE 7: MLP2 (+res from xf1_t, f32 out).
// ---------------------------------------------------------------------------
template <int MODE>
__global__ __launch_bounds__(256, 4) void gemm3(
    const unsigned short* __restrict__ W, const unsigned short* __restrict__ Bn,
    const float* __restrict__ bias, const float* __restrict__ resf,
    const unsigned short* __restrict__ resb, void* __restrict__ outv,
    float* __restrict__ stats, const float* __restrict__ bnin,
    const float* __restrict__ g, const float* __restrict__ bb, int M, int K) {
  int bid = blockIdx.x;
  int b = bid & 7;                 // XCD-grouped: each XCD owns one batch
  int rest = bid >> 3;
  int n0 = (rest & 15) * 64, m0 = (rest >> 4) * 64;
  int t = threadIdx.x, lane = t & 63, w = t >> 6;
  int ml = lane & 15, quad = lane >> 4;

  __shared__ unsigned short Wt[64][64];
  __shared__ unsigned short Yt[64][64];
  __shared__ float Scl[256], Shf[256];

  if (MODE == 6) {   // precompute BN2 scale/shift (c = t)
    float m = bnin[t] * (1.0f / 8192.0f);
    float var = bnin[256 + t] * (1.0f / 8192.0f) - m * m;
    float scl = g[t] * rsqrtf(var + 1e-5f);
    Scl[t] = scl;
    Shf[t] = bb[t] - m * scl;
    __syncthreads();
  }

  const unsigned short* Bp = Bn + (size_t)b * 1024 * K;
  int sr = t >> 2, scg = (t & 3) * 16;                 // mode-6 B staging coords
  const unsigned short* brow = Bp + (size_t)(n0 + sr) * K + scg;

  // gload staging coords (per wave-call of 8 rows)
  int lrow = lane >> 3;                 // 0..7 within call
  int cgs  = (lane & 7) ^ lrow;         // pre-swizzled source col-group

  char* Wb = (char*)&Wt[0][0];
  char* Yb = (char*)&Yt[0][0];
  const int swa = (ml & 7) << 4;        // read-side XOR byte mask

  floatx4 acc[4];
  #pragma unroll
  for (int i = 0; i < 4; ++i) acc[i] = (floatx4){0.f, 0.f, 0.f, 0.f};

  for (int k0 = 0; k0 < K; k0 += 64) {
    // --- stage W tile: 2 gload calls/wave (8 rows each) ---
    #pragma unroll
    for (int j = 0; j < 2; ++j) {
      int row = w * 16 + j * 8 + lrow;
      gload16(W + (size_t)(m0 + row) * K + k0 + cgs * 8, &Wt[w * 16 + j * 8][0]);
    }
    if (MODE == 6) {   // BN2-apply inline: y2 = xf1*scl + shf -> swizzled store
      uint4 r0 = *(const uint4*)(brow + k0);
      uint4 r1 = *(const uint4*)(brow + k0 + 8);
      int cb = k0 + scg;
      float4 s0 = *(const float4*)&Scl[cb],     h0 = *(const float4*)&Shf[cb];
      float4 s1 = *(const float4*)&Scl[cb + 4], h1 = *(const float4*)&Shf[cb + 4];
      float4 s2 = *(const float4*)&Scl[cb + 8], h2 = *(const float4*)&Shf[cb + 8];
      float4 s3 = *(const float4*)&Scl[cb + 12], h3 = *(const float4*)&Shf[cb + 12];
      uint4 o0, o1;
      o0.x = f2b2(fmaf(b2f(r0.x & 0xffff), s0.x, h0.x), fmaf(b2f(r0.x >> 16), s0.y, h0.y));
      o0.y = f2b2(fmaf(b2f(r0.y & 0xffff), s0.z, h0.z), fmaf(b2f(r0.y >> 16), s0.w, h0.w));
      o0.z = f2b2(fmaf(b2f(r0.z & 0xffff), s1.x, h1.x), fmaf(b2f(r0.z >> 16), s1.y, h1.y));
      o0.w = f2b2(fmaf(b2f(r0.w & 0xffff), s1.z, h1.z), fmaf(b2f(r0.w >> 16), s1.w, h1.w));
      o1.x = f2b2(fmaf(b2f(r1.x & 0xffff), s2.x, h2.x), fmaf(b2f(r1.x >> 16), s2.y, h2.y));
      o1.y = f2b2(fmaf(b2f(r1.y & 0xffff), s2.z, h2.z), fmaf(b2f(r1.y >> 16), s2.w, h2.w));
      o1.z = f2b2(fmaf(b2f(r1.z & 0xffff), s3.x, h3.x), fmaf(b2f(r1.z >> 16), s3.y, h3.y));
      o1.w = f2b2(fmaf(b2f(r1.w & 0xffff), s3.z, h3.z), fmaf(b2f(r1.w >> 16), s3.w, h3.w));
      int sg0 = (t & 3) * 2, sg1 = sg0 + 1;           // logical 8-short groups
      *(uint4*)(Yb + sr * 128 + ((sg0 ^ (sr & 7)) << 4)) = o0;
      *(uint4*)(Yb + sr * 128 + ((sg1 ^ (sr & 7)) << 4)) = o1;
    } else {
      // --- stage B tile via gload, same pre-swizzle ---
      #pragma unroll
      for (int j = 0; j < 2; ++j) {
        int row = w * 16 + j * 8 + lrow;
        gload16(Bp + (size_t)(n0 + row) * K + k0 + cgs * 8, &Yt[w * 16 + j * 8][0]);
      }
    }
    __syncthreads();
    int arow = w * 16 + ml;
    short8 a0 = *(const short8*)(Wb + arow * 128 + ((quad << 4) ^ swa));
    short8 a1 = *(const short8*)(Wb + arow * 128 + (((quad + 4) << 4) ^ swa));
    #pragma unroll
    for (int nt2 = 0; nt2 < 4; ++nt2) {
      int brw = nt2 * 16 + ml;
      short8 b0 = *(const short8*)(Yb + brw * 128 + ((quad << 4) ^ swa));
      short8 b1 = *(const short8*)(Yb + brw * 128 + (((quad + 4) << 4) ^ swa));
      acc[nt2] = __builtin_amdgcn_mfma_f32_16x16x32_bf16(a0, b0, acc[nt2], 0, 0, 0);
      acc[nt2] = __builtin_amdgcn_mfma_f32_16x16x32_bf16(a1, b1, acc[nt2], 0, 0, 0);
    }
    __syncthreads();
  }

  int row_base = m0 + w * 16 + quad * 4;

  if (MODE == 4) {
    int hh = row_base >> 4;       // 0..95
    float b0 = bias[row_base + 0], b1 = bias[row_base + 1];
    float b2 = bias[row_base + 2], b3 = bias[row_base + 3];
    if (hh < 32) {                // q (hh<16) or k
      unsigned short* qkout = (unsigned short*)outv + ((hh < 16) ? 0 : 2097152);
      float os = (hh < 16) ? QK_SC : 1.0f;
      int head = hh & 15, kd0 = row_base & 15;
      #pragma unroll
      for (int c = 0; c < 4; ++c) {
        int col = n0 + c * 16 + ml;
        uint2 pw;
        pw.x = f2b2((acc[c][0] + b0) * os, (acc[c][1] + b1) * os);
        pw.y = f2b2((acc[c][2] + b2) * os, (acc[c][3] + b3) * os);
        *(uint2*)&qkout[(((size_t)b * 16 + head) * 1024 + col) * 16 + kd0] = pw;
      }
    } else {                      // v: k-major [b][d][1024]
      unsigned short* vout = (unsigned short*)outv + 4194304;
      int d0 = row_base - 512;
      #pragma unroll
      for (int c = 0; c < 4; ++c) {
        int col = n0 + c * 16 + ml;
        vout[((size_t)b * 1024 + d0 + 0) * 1024 + col] = f2b(acc[c][0] + b0);
        vout[((size_t)b * 1024 + d0 + 1) * 1024 + col] = f2b(acc[c][1] + b1);
        vout[((size_t)b * 1024 + d0 + 2) * 1024 + col] = f2b(acc[c][2] + b2);
        vout[((size_t)b * 1024 + d0 + 3) * 1024 + col] = f2b(acc[c][3] + b3);
      }
    }
  } else if (MODE == 5) {          // proj -> xf1_t n-major bf16 + stats
    unsigned short* outp = (unsigned short*)outv;
    float vsum[4] = {0.f, 0.f, 0.f, 0.f}, vsq[4] = {0.f, 0.f, 0.f, 0.f};
    #pragma unroll
    for (int c = 0; c < 4; ++c) {
      int col = n0 + c * 16 + ml;
      float v0 = acc[c][0] + bias[row_base + 0] + resf[((size_t)b * 256 + row_base + 0) * 1024 + col];
      float v1 = acc[c][1] + bias[row_base + 1] + resf[((size_t)b * 256 + row_base + 1) * 1024 + col];
      float v2 = acc[c][2] + bias[row_base + 2] + resf[((size_t)b * 256 + row_base + 2) * 1024 + col];
      float v3 = acc[c][3] + bias[row_base + 3] + resf[((size_t)b * 256 + row_base + 3) * 1024 + col];
      vsum[0] += v0; vsq[0] += v0 * v0;
      vsum[1] += v1; vsq[1] += v1 * v1;
      vsum[2] += v2; vsq[2] += v2 * v2;
      vsum[3] += v3; vsq[3] += v3 * v3;
      uint2 pw; pw.x = f2b2(v0, v1); pw.y = f2b2(v2, v3);
      *(uint2*)&outp[((size_t)b * 1024 + col) * 256 + row_base] = pw;
    }
    #pragma unroll
    for (int r = 0; r < 4; ++r) {
      float s = vsum[r], q = vsq[r];
      #pragma unroll
      for (int o = 1; o < 16; o <<= 1) { s += __shfl_xor(s, o, 64); q += __shfl_xor(q, o, 64); }
      if (ml == 0) {
        atomicAdd(stats + row_base + r, s);
        atomicAdd(stats + 256 + row_base + r, q);
      }
    }
  } else if (MODE == 6) {          // MLP1 -> hb_t n-major bf16 + relu6
    unsigned short* outp = (unsigned short*)outv;
    #pragma unroll
    for (int c = 0; c < 4; ++c) {
      int col = n0 + c * 16 + ml;
      float v0 = fminf(fmaxf(acc[c][0] + bias[row_base + 0], 0.f), 6.f);
      float v1 = fminf(fmaxf(acc[c][1] + bias[row_base + 1], 0.f), 6.f);
      float v2 = fminf(fmaxf(acc[c][2] + bias[row_base + 2], 0.f), 6.f);
      float v3 = fminf(fmaxf(acc[c][3] + bias[row_base + 3], 0.f), 6.f);
      uint2 pw; pw.x = f2b2(v0, v1); pw.y = f2b2(v2, v3);
      *(uint2*)&outp[((size_t)b * 1024 + col) * 1024 + row_base] = pw;
    }
  } else {                          // MODE 7: MLP2 -> d_out f32 + res from xf1_t
    float* outp = (float*)outv;
    #pragma unroll
    for (int c = 0; c < 4; ++c) {
      int col = n0 + c * 16 + ml;
      uint2 rv = *(const uint2*)(resb + ((size_t)b * 1024 + col) * 256 + row_base);
      float r0 = b2f((unsigned short)(rv.x & 0xffff));
      float r1 = b2f((unsigned short)(rv.x >> 16));
      float r2 = b2f((unsigned short)(rv.y & 0xffff));
      float r3 = b2f((unsigned short)(rv.y >> 16));
      outp[((size_t)b * 256 + row_base + 0) * 1024 + col] = acc[c][0] + bias[row_base + 0] + r0;
      outp[((size_t)b * 256 + row_base + 1) * 1024 + col] = acc[c][1] + bias[row_base + 1] + r1;
      outp[((size_t)b * 256 + row_base + 2) * 1024 + col] = acc[c][2] + bias[row_base + 2] + r2;
      outp[((size_t)b * 256 + row_base + 3) * 1024 + col] = acc[c][3] + bias[row_base + 3] + r3;
    }
  }
}

// ---------------------------------------------------------------------------
// Attention R18: software pipeline, macro form (rule #20 safe: no lambdas,
// no address-taken arrays; all indices compile-time). Schedule per tile i:
//   readP(i-1) -> QK(i) -> loadK(i+2) -> PV(i-1) -> loadV(i+2).
// launch_bounds(256,2): working set ~166 VGPR -> 12 waves/CU = 3/SIMD
// (same as today's effective 3.2) but K/V loads age a full phase before use.
// ---------------------------------------------------------------------------
#define LOADK(dst, mc)                                                         \
  {                                                                            \
    _Pragma("unroll") for (int tt = 0; tt < 2; ++tt) {                         \
      short8 z = {0, 0, 0, 0, 0, 0, 0, 0};                                     \
      if (quad < 2)                                                            \
        z = *(const short8*)(kp + (size_t)((mc) + tt * 16 + ml) * 16 + quad * 8); \
      dst[tt] = z;                                                             \
    }                                                                          \
  }

#define LOADV(dst, mc)                                                         \
  {                                                                            \
    _Pragma("unroll") for (int dt = 0; dt < 4; ++dt)                           \
      dst[dt] = *(const short8*)(vp + (size_t)(dt * 16 + ml) * 1024 + (mc) + quad * 8); \
  }

#define QKSTEP(kf, bufidx)                                                     \
  {                                                                            \
    _Pragma("unroll") for (int rg = 0; rg < 2; ++rg) {                         \
      _Pragma("unroll") for (int tt = 0; tt < 2; ++tt) {                       \
        floatx4 s = __builtin_amdgcn_mfma_f32_16x16x32_bf16(kf[tt], qf[rg], zf, 0, 0, 0); \
        float p0 = __builtin_amdgcn_exp2f(s[0]);                               \
        float p1 = __builtin_amdgcn_exp2f(s[1]);                               \
        float p2 = __builtin_amdgcn_exp2f(s[2]);                               \
        float p3 = __builtin_amdgcn_exp2f(s[3]);                               \
        if (rg == 0) psum0 += (p0 + p1) + (p2 + p3);                           \
        else         psum1 += (p0 + p1) + (p2 + p3);                           \
        uint2 pw; pw.x = f2b2(p0, p1); pw.y = f2b2(p2, p3);                    \
        *(uint2*)&Pscr[w][bufidx][rg][ml][tt * 8 + quad * 2] = pw;             \
      }                                                                        \
    }                                                                          \
  }

#define READP(bufidx, pa)                                                      \
  {                                                                            \
    _Pragma("unroll") for (int rg = 0; rg < 2; ++rg) {                         \
      uint2 a0 = *(const uint2*)&Pscr[w][bufidx][rg][ml][quad * 4];            \
      uint2 a1 = *(const uint2*)&Pscr[w][bufidx][rg][ml][quad * 4 + 2];        \
      union { uint4 u; short8 s; } cv;                                         \
      cv.u = make_uint4(a0.x, a0.y, a1.x, a1.y);                               \
      pa[rg] = cv.s;                                                           \
    }                                                                          \
  }

#define PVSTEP(pa, vf)                                                         \
  {                                                                            \
    _Pragma("unroll") for (int rg = 0; rg < 2; ++rg)                           \
      _Pragma("unroll") for (int dt = 0; dt < 4; ++dt)                         \
        oacc[rg][dt] = __builtin_amdgcn_mfma_f32_16x16x32_bf16(pa[rg], vf[dt], oacc[rg][dt], 0, 0, 0); \
  }

__global__ __launch_bounds__(256, 2) void attn_kernel(
    const unsigned short* __restrict__ qt, const unsigned short* __restrict__ kt,
    const unsigned short* __restrict__ vt, unsigned short* __restrict__ ot) {
  int bx0 = blockIdx.x;
  int bx = (bx0 & 7) * 128 + (bx0 >> 3);   // bijective XCD grouping
  int nt = bx & 7, h = (bx >> 3) & 15, b = bx >> 7;
  int tid = threadIdx.x, lane = tid & 63, w = tid >> 6;
  int ml = lane & 15, quad = lane >> 4;

  __shared__ unsigned int Pscr[4][2][2][16][18];  // [wave][buf][rg][n][m-packed u32]
  __shared__ float Ssum[4][2][16];

  const int n0 = nt * 128 + w * 32;
  const size_t qk_row = ((size_t)b * 16 + h) * 1024;

  short8 qf[2];
  #pragma unroll
  for (int rg = 0; rg < 2; ++rg) {
    short8 z = {0, 0, 0, 0, 0, 0, 0, 0};
    if (quad < 2)
      z = *(const short8*)(qt + (qk_row + n0 + rg * 16 + ml) * 16 + quad * 8);
    qf[rg] = z;
  }

  const floatx4 zf = {0.f, 0.f, 0.f, 0.f};
  floatx4 oacc[2][4];
  #pragma unroll
  for (int rg = 0; rg < 2; ++rg)
    #pragma unroll
    for (int dt = 0; dt < 4; ++dt) oacc[rg][dt] = zf;
  float psum0 = 0.f, psum1 = 0.f;

  const unsigned short* kp = kt + qk_row * 16;
  const unsigned short* vp = vt + ((size_t)b * 1024 + h * 64) * 1024;

  short8 kfA[2], kfB[2], vfA[4], vfB[4], pa[2];

  // prologue: tile0 in A, tile1's K/V prefetched into B
  LOADK(kfA, 0); LOADV(vfA, 0);
  QKSTEP(kfA, 0);                    // P(0) -> buf0
  LOADK(kfB, 32); LOADV(vfB, 32);

  // steady state: j covers tiles (2j+1, 2j+2), j = 0..14 -> tiles 1..30
  for (int j = 0; j < 15; ++j) {
    int mc = j * 64;
    // --- odd tile i = 2j+1 (K in B, V in B), PV of even tile 2j (V in A) ---
    READP(0, pa);                    // P(2j)
    QKSTEP(kfB, 1);                  // P(2j+1) -> buf1; kfB free
    LOADK(kfA, mc + 64);             // K(2j+2) -> A
    PVSTEP(pa, vfA);                 // PV(2j); vfA free
    LOADV(vfA, mc + 64);             // V(2j+2) -> A
    // --- even tile i = 2j+2 (K in A, V in A), PV of odd tile (V in B) ---
    READP(1, pa);                    // P(2j+1)
    QKSTEP(kfA, 0);                  // P(2j+2) -> buf0; kfA free
    LOADK(kfB, mc + 96);             // K(2j+3) -> B   (j=14: K(31))
    PVSTEP(pa, vfB);                 // PV(2j+1); vfB free
    LOADV(vfB, mc + 96);             // V(2j+3) -> B   (j=14: V(31))
  }

  // epilogue: tile 31 QK + PV(30) + PV(31)
  READP(0, pa);                      // P(30)
  QKSTEP(kfB, 1);                    // P(31) -> buf1 (kfB = K31)
  PVSTEP(pa, vfA);                   // PV(30), vfA = V30
  READP(1, pa);                      // P(31)
  PVSTEP(pa, vfB);                   // PV(31), vfB = V31

  {
    float s0 = psum0;
    s0 += __shfl_xor(s0, 16, 64);
    s0 += __shfl_xor(s0, 32, 64);
    float s1 = psum1;
    s1 += __shfl_xor(s1, 16, 64);
    s1 += __shfl_xor(s1, 32, 64);
    if (lane < 16) { Ssum[w][0][ml] = s0; Ssum[w][1][ml] = s1; }
  }
  #pragma unroll
  for (int rg = 0; rg < 2; ++rg) {
    float4 sv = *(const float4*)&Ssum[w][rg][quad * 4];
    float inv0 = 1.0f / sv.x, inv1 = 1.0f / sv.y;
    float inv2 = 1.0f / sv.z, inv3 = 1.0f / sv.w;
    int nbase = n0 + rg * 16 + quad * 4;
    #pragma unroll
    for (int dt = 0; dt < 4; ++dt) {
      int dg = h * 64 + dt * 16 + ml;
      size_t obase = (((size_t)b << 10) + nbase) * 1024 + dg;
      ot[obase + 0 * 1024] = f2b(oacc[rg][dt][0] * inv0);
      ot[obase + 1 * 1024] = f2b(oacc[rg][dt][1] * inv1);
      ot[obase + 2 * 1024] = f2b(oacc[rg][dt][2] * inv2);
      ot[obase + 3 * 1024] = f2b(oacc[rg][dt][3] * inv3);
    }
  }
}

// ---------------------------------------------------------------------------
extern "C" void kernel_launch(void* const* d_in, const int* in_sizes, int n_in,
                              void* d_out, int out_size, void* d_ws, size_t ws_size,
                              hipStream_t stream) {
  const float* x   = (const float*)d_in[0];
  const float* g1  = (const float*)d_in[1];
  const float* b1  = (const float*)d_in[2];
  const float* wq  = (const float*)d_in[3];
  const float* bq  = (const float*)d_in[4];
  const float* wk  = (const float*)d_in[5];
  const float* bk  = (const float*)d_in[6];
  const float* wv  = (const float*)d_in[7];
  const float* bv  = (const float*)d_in[8];
  const float* wp  = (const float*)d_in[9];
  const float* bp  = (const float*)d_in[10];
  const float* g2  = (const float*)d_in[11];
  const float* b2  = (const float*)d_in[12];
  const float* w1  = (const float*)d_in[13];
  const float* bb1 = (const float*)d_in[14];
  const float* w2  = (const float*)d_in[15];
  const float* bb2 = (const float*)d_in[16];

  char* ws = (char*)d_ws;
  float* bnacc   = (float*)ws;                  // 1024 f: sum1,sq1 | sum2,sq2
  float* biasqkv = (float*)(ws + 4096);         // 1536 f
  unsigned short* y_t  = (unsigned short*)(ws + 16384);    // bf16 [8][1024][256]
  unsigned short* qt   = y_t + (size_t)2 * 1024 * 1024;    // bf16 [8][16][1024][16]
  unsigned short* kt   = qt  + (size_t)2 * 1024 * 1024;    // = qt + 2097152
  unsigned short* vt   = kt  + (size_t)2 * 1024 * 1024;    // = qt + 4194304
  unsigned short* ot   = vt  + (size_t)8 * 1024 * 1024;    // bf16 [8][1024][1024] n-major
  unsigned short* xf1t = ot  + (size_t)8 * 1024 * 1024;    // bf16 [8][1024][256] n-major
  unsigned short* wb   = xf1t + (size_t)2 * 1024 * 1024;
  unsigned short* hb_t = ot;          // reuse: ot dead after proj
  float* outp = (float*)d_out;

  unsigned short* wqkvb = wb;         // rows 0..255 wq | 256..511 wk | 512..1535 wv
  unsigned short* wpb = wb + 393216;
  unsigned short* w1b = wb + 655360;
  unsigned short* w2b = wb + 917504;
  const unsigned short* nub = nullptr;
  const float* nuf = nullptr;

  hipMemsetAsync(bnacc, 0, 4096, stream);
  prep<<<dim3(3206), dim3(256), 0, stream>>>(
      wq, wk, wv, wp, w1, w2, wb, x, bnacc, bq, bk, bv, biasqkv);

  // --- attention branch ---
  bn_apply_t<<<dim3(16, 4, 8), dim3(256), 0, stream>>>(x, bnacc, g1, b1, y_t);
  gemm3<4><<<dim3(3072), dim3(256), 0, stream>>>(
      wqkvb, y_t, biasqkv, nuf, nub, qt, nullptr, nuf, nuf, nuf, 1536, 256);
  attn_kernel<<<dim3(1024), dim3(256), 0, stream>>>(qt, kt, vt, ot);
  gemm3<5><<<dim3(512), dim3(256), 0, stream>>>(
      wpb, ot, bp, x, nub, xf1t, bnacc + 512, nuf, nuf, nuf, 256, 1024);

  // --- MLP branch ---
  gemm3<6><<<dim3(2048), dim3(256), 0, stream>>>(
      w1b, xf1t, bb1, nuf, nub, hb_t, nullptr, bnacc + 512, g2, b2, 1024, 256);
  gemm3<7><<<dim3(512), dim3(256), 0, stream>>>(
      w2b, hb_t, bb2, nuf, xf1t, outp, nullptr, nuf, nuf, nuf, 256, 1024);
}

// Round 7
// 208.679 us; speedup vs baseline: 1.2274x; 1.2274x over previous
//
#include <hip/hip_runtime.h>
#include <hip/hip_bf16.h>
#include <cstdint>

// ---------------------------------------------------------------------------
// TextBlock: BN -> {q,k,v} -> MHSA (NH=16, KD=16, D=64, N=1024) -> proj -> +res
//            -> BN -> MLP(1024, relu6) -> +res.   B=8, C=256.
// I/O FLOAT32. Intermediates bf16 for MFMA, fp32 accumulation.
// R13: XCD swizzle. R14/R18 FAILED: compiler sinks register global-loads to
//      use (3x confirmed) -> no source-level reg pipeline possible.
// R15 FAILED: forced 8 waves -> spill. R16 WIN: gemm gload_lds w16 (239.9us).
// R17 NEUTRAL: gemm dbuf (TLP already hides it at 4 blocks/CU).
// R19: attn K/V -> double-buffered global_load_lds staging. Mechanism the
//      compiler can't defeat: gload_lds issues where placed, vmcnt(0) drain
//      lands at the end-of-iter barrier AFTER the compute phase -> global
//      latency (~600cy) hidden behind QK+exp+PV. Bonus: all 4 waves share
//      the SAME K/V tile -> cooperative staging dedups 4x redundant loads.
//      V staged rule-#21 (linear dest + src cg^=(row&3) + XOR read); K tile
//      is contiguous 1KB (linear, 2-way free). ds_read replaces global in
//      the chain (~120 vs ~600 cyc). One barrier/iter. LDS 29.2KB, 4 blk/CU.
// ---------------------------------------------------------------------------

typedef __attribute__((ext_vector_type(8))) short short8;
typedef __attribute__((ext_vector_type(4))) float floatx4;

#define QK_SC 5.770780163555851f   // sqrt(kd)=4 times log2(e), folded into Q

__device__ __forceinline__ float b2f(unsigned short u) {
  union { unsigned int i; float f; } x; x.i = ((unsigned int)u) << 16; return x.f;
}
__device__ __forceinline__ unsigned short f2b(float f) {
  union { float f; unsigned int i; } x; x.f = f;
  unsigned int r = x.i + 0x7FFFu + ((x.i >> 16) & 1u);   // RNE
  return (unsigned short)(r >> 16);
}
// packed f32x2 -> bf16x2 (v_cvt_pk_bf16_f32 on gfx950)
__device__ __forceinline__ unsigned int f2b2(float a, float b) {
  __hip_bfloat162 h = __float22bfloat162_rn(make_float2(a, b));
  union { __hip_bfloat162 v; unsigned int u; } x; x.v = h; return x.u;
}
// async global->LDS, 16B per lane; LDS dest is wave-uniform base + lane*16.
__device__ __forceinline__ void gload16(const unsigned short* g, unsigned short* l) {
  __builtin_amdgcn_global_load_lds(
      (const __attribute__((address_space(1))) unsigned int*)g,
      (__attribute__((address_space(3))) unsigned int*)l, 16, 0, 0);
}

// ---------------------------------------------------------------------------
// prep: blocks 0..1151 convert the 6 weight mats f32->bf16 into wb;
//       blocks 1152..3199 accumulate BN1 partial sums of x into bnacc;
//       blocks 3200..3205 concat bq|bk|bv into biasqkv.
// ---------------------------------------------------------------------------
__global__ __launch_bounds__(256) void prep(
    const float* __restrict__ s0, const float* __restrict__ s1,
    const float* __restrict__ s2, const float* __restrict__ s3,
    const float* __restrict__ s4, const float* __restrict__ s5,
    unsigned short* __restrict__ dst,
    const float* __restrict__ x, float* __restrict__ acc,
    const float* __restrict__ bq, const float* __restrict__ bk,
    const float* __restrict__ bv, float* __restrict__ biasqkv) {
  int blk = blockIdx.x, t = threadIdx.x;
  if (blk < 1152) {
    int i = blk * 256 + t;   // float4-group index
    if (i >= 294912) return;
    const float* s; int li; size_t dbase;
    if (i < 16384)       { s = s0; li = i;          dbase = 0; }
    else if (i < 32768)  { s = s1; li = i - 16384;  dbase = 65536; }
    else if (i < 98304)  { s = s2; li = i - 32768;  dbase = 131072; }
    else if (i < 163840) { s = s3; li = i - 98304;  dbase = 393216; }
    else if (i < 229376) { s = s4; li = i - 163840; dbase = 655360; }
    else                 { s = s5; li = i - 229376; dbase = 917504; }
    float4 v = ((const float4*)s)[li];
    uint2 o; o.x = f2b2(v.x, v.y); o.y = f2b2(v.z, v.w);
    ((uint2*)(dst + dbase))[li] = o;
  } else if (blk < 3200) {
    int blk2 = blk - 1152;
    int b = blk2 >> 8, c = blk2 & 255;
    const float* p = x + (((size_t)(b * 256 + c)) << 10);
    float4 v = ((const float4*)p)[t];
    float s = (v.x + v.y) + (v.z + v.w);
    float s2 = (v.x * v.x + v.y * v.y) + (v.z * v.z + v.w * v.w);
    #pragma unroll
    for (int o = 32; o > 0; o >>= 1) { s += __shfl_down(s, o, 64); s2 += __shfl_down(s2, o, 64); }
    __shared__ float rs[4], rs2[4];
    int w = t >> 6;
    if ((t & 63) == 0) { rs[w] = s; rs2[w] = s2; }
    __syncthreads();
    if (t == 0) {
      atomicAdd(acc + c, (rs[0] + rs[1]) + (rs[2] + rs[3]));
      atomicAdd(acc + 256 + c, (rs2[0] + rs2[1]) + (rs2[2] + rs2[3]));
    }
  } else {
    int i = (blk - 3200) * 256 + t;   // 0..1535
    float v = (i < 256) ? bq[i] : (i < 512) ? bk[i - 256] : bv[i - 512];
    biasqkv[i] = v;
  }
}

// ---------------------------------------------------------------------------
// BN apply + transpose (finalize fused): x[b][c][n] f32 -> y_t[b][n][c] bf16.
// ---------------------------------------------------------------------------
__global__ __launch_bounds__(256) void bn_apply_t(
    const float* __restrict__ x, const float* __restrict__ acc,
    const float* __restrict__ g, const float* __restrict__ bb,
    unsigned short* __restrict__ yt) {
  int nt = blockIdx.x, ct = blockIdx.y, b = blockIdx.z;
  int t = threadIdx.x;
  __shared__ unsigned short T[64][72];
  {
    int r = t >> 2, g4 = (t & 3) * 16;
    int c = ct * 64 + r;
    float m = acc[c] * (1.0f / 8192.0f);
    float var = acc[256 + c] * (1.0f / 8192.0f) - m * m;
    float scl = g[c] * rsqrtf(var + 1e-5f);
    float shf = bb[c] - m * scl;
    const float* p = x + (((size_t)(b * 256 + c)) << 10) + nt * 64 + g4;
    float4 u0 = *(const float4*)(p);
    float4 u1 = *(const float4*)(p + 4);
    float4 u2 = *(const float4*)(p + 8);
    float4 u3 = *(const float4*)(p + 12);
    uint4 o0, o1;
    o0.x = f2b2(fmaf(u0.x, scl, shf), fmaf(u0.y, scl, shf));
    o0.y = f2b2(fmaf(u0.z, scl, shf), fmaf(u0.w, scl, shf));
    o0.z = f2b2(fmaf(u1.x, scl, shf), fmaf(u1.y, scl, shf));
    o0.w = f2b2(fmaf(u1.z, scl, shf), fmaf(u1.w, scl, shf));
    o1.x = f2b2(fmaf(u2.x, scl, shf), fmaf(u2.y, scl, shf));
    o1.y = f2b2(fmaf(u2.z, scl, shf), fmaf(u2.w, scl, shf));
    o1.z = f2b2(fmaf(u3.x, scl, shf), fmaf(u3.y, scl, shf));
    o1.w = f2b2(fmaf(u3.z, scl, shf), fmaf(u3.w, scl, shf));
    *(uint4*)&T[r][g4] = o0;
    *(uint4*)&T[r][g4 + 8] = o1;
  }
  __syncthreads();
  {
    int nr = t >> 2, cg = (t & 3) * 16;
    unsigned int ob[8];
    #pragma unroll
    for (int j = 0; j < 8; ++j) {
      unsigned int lo = T[cg + 2 * j][nr];
      unsigned int hi = T[cg + 2 * j + 1][nr];
      ob[j] = lo | (hi << 16);
    }
    unsigned short* orow = yt + ((size_t)(b * 1024 + nt * 64 + nr)) * 256 + ct * 64 + cg;
    *(uint4*)&orow[0] = make_uint4(ob[0], ob[1], ob[2], ob[3]);
    *(uint4*)&orow[8] = make_uint4(ob[4], ob[5], ob[6], ob[7]);
  }
}

// ---------------------------------------------------------------------------
// MFMA GEMM (64x64, BK=64, (256,4)):  out = W[M,K] @ Bn_b[N,K]^T + bias
// R16 staging (proven): global_load_lds w16 into UNPADDED [64][64] LDS.
//   Rule #21 both-sides swizzle: linear LDS dest, pre-swizzled global source
//   col-group (s ^ (l>>3)), read-side XOR ((q ^ (row&7))<<4).
// MODE 4: fused QKV. MODE 5: proj (+res, BN2 stats, n-major out).
// MODE 6: MLP1 (inline BN2 on B staging -> swizzled stores; relu6; n-major).
// MODE 7: MLP2 (+res from xf1_t, f32 out).
// ---------------------------------------------------------------------------
template <int MODE>
__global__ __launch_bounds__(256, 4) void gemm3(
    const unsigned short* __restrict__ W, const unsigned short* __restrict__ Bn,
    const float* __restrict__ bias, const float* __restrict__ resf,
    const unsigned short* __restrict__ resb, void* __restrict__ outv,
    float* __restrict__ stats, const float* __restrict__ bnin,
    const float* __restrict__ g, const float* __restrict__ bb, int M, int K) {
  int bid = blockIdx.x;
  int b = bid & 7;                 // XCD-grouped: each XCD owns one batch
  int rest = bid >> 3;
  int n0 = (rest & 15) * 64, m0 = (rest >> 4) * 64;
  int t = threadIdx.x, lane = t & 63, w = t >> 6;
  int ml = lane & 15, quad = lane >> 4;

  __shared__ unsigned short Wt[64][64];
  __shared__ unsigned short Yt[64][64];
  __shared__ float Scl[256], Shf[256];

  if (MODE == 6) {   // precompute BN2 scale/shift (c = t)
    float m = bnin[t] * (1.0f / 8192.0f);
    float var = bnin[256 + t] * (1.0f / 8192.0f) - m * m;
    float scl = g[t] * rsqrtf(var + 1e-5f);
    Scl[t] = scl;
    Shf[t] = bb[t] - m * scl;
    __syncthreads();
  }

  const unsigned short* Bp = Bn + (size_t)b * 1024 * K;
  int sr = t >> 2, scg = (t & 3) * 16;                 // mode-6 B staging coords
  const unsigned short* brow = Bp + (size_t)(n0 + sr) * K + scg;

  // gload staging coords (per wave-call of 8 rows)
  int lrow = lane >> 3;                 // 0..7 within call
  int cgs  = (lane & 7) ^ lrow;         // pre-swizzled source col-group

  char* Wb = (char*)&Wt[0][0];
  char* Yb = (char*)&Yt[0][0];
  const int swa = (ml & 7) << 4;        // read-side XOR byte mask

  floatx4 acc[4];
  #pragma unroll
  for (int i = 0; i < 4; ++i) acc[i] = (floatx4){0.f, 0.f, 0.f, 0.f};

  for (int k0 = 0; k0 < K; k0 += 64) {
    // --- stage W tile: 2 gload calls/wave (8 rows each) ---
    #pragma unroll
    for (int j = 0; j < 2; ++j) {
      int row = w * 16 + j * 8 + lrow;
      gload16(W + (size_t)(m0 + row) * K + k0 + cgs * 8, &Wt[w * 16 + j * 8][0]);
    }
    if (MODE == 6) {   // BN2-apply inline: y2 = xf1*scl + shf -> swizzled store
      uint4 r0 = *(const uint4*)(brow + k0);
      uint4 r1 = *(const uint4*)(brow + k0 + 8);
      int cb = k0 + scg;
      float4 s0 = *(const float4*)&Scl[cb],     h0 = *(const float4*)&Shf[cb];
      float4 s1 = *(const float4*)&Scl[cb + 4], h1 = *(const float4*)&Shf[cb + 4];
      float4 s2 = *(const float4*)&Scl[cb + 8], h2 = *(const float4*)&Shf[cb + 8];
      float4 s3 = *(const float4*)&Scl[cb + 12], h3 = *(const float4*)&Shf[cb + 12];
      uint4 o0, o1;
      o0.x = f2b2(fmaf(b2f(r0.x & 0xffff), s0.x, h0.x), fmaf(b2f(r0.x >> 16), s0.y, h0.y));
      o0.y = f2b2(fmaf(b2f(r0.y & 0xffff), s0.z, h0.z), fmaf(b2f(r0.y >> 16), s0.w, h0.w));
      o0.z = f2b2(fmaf(b2f(r0.z & 0xffff), s1.x, h1.x), fmaf(b2f(r0.z >> 16), s1.y, h1.y));
      o0.w = f2b2(fmaf(b2f(r0.w & 0xffff), s1.z, h1.z), fmaf(b2f(r0.w >> 16), s1.w, h1.w));
      o1.x = f2b2(fmaf(b2f(r1.x & 0xffff), s2.x, h2.x), fmaf(b2f(r1.x >> 16), s2.y, h2.y));
      o1.y = f2b2(fmaf(b2f(r1.y & 0xffff), s2.z, h2.z), fmaf(b2f(r1.y >> 16), s2.w, h2.w));
      o1.z = f2b2(fmaf(b2f(r1.z & 0xffff), s3.x, h3.x), fmaf(b2f(r1.z >> 16), s3.y, h3.y));
      o1.w = f2b2(fmaf(b2f(r1.w & 0xffff), s3.z, h3.z), fmaf(b2f(r1.w >> 16), s3.w, h3.w));
      int sg0 = (t & 3) * 2, sg1 = sg0 + 1;           // logical 8-short groups
      *(uint4*)(Yb + sr * 128 + ((sg0 ^ (sr & 7)) << 4)) = o0;
      *(uint4*)(Yb + sr * 128 + ((sg1 ^ (sr & 7)) << 4)) = o1;
    } else {
      // --- stage B tile via gload, same pre-swizzle ---
      #pragma unroll
      for (int j = 0; j < 2; ++j) {
        int row = w * 16 + j * 8 + lrow;
        gload16(Bp + (size_t)(n0 + row) * K + k0 + cgs * 8, &Yt[w * 16 + j * 8][0]);
      }
    }
    __syncthreads();
    int arow = w * 16 + ml;
    short8 a0 = *(const short8*)(Wb + arow * 128 + ((quad << 4) ^ swa));
    short8 a1 = *(const short8*)(Wb + arow * 128 + (((quad + 4) << 4) ^ swa));
    #pragma unroll
    for (int nt2 = 0; nt2 < 4; ++nt2) {
      int brw = nt2 * 16 + ml;
      short8 b0 = *(const short8*)(Yb + brw * 128 + ((quad << 4) ^ swa));
      short8 b1 = *(const short8*)(Yb + brw * 128 + (((quad + 4) << 4) ^ swa));
      acc[nt2] = __builtin_amdgcn_mfma_f32_16x16x32_bf16(a0, b0, acc[nt2], 0, 0, 0);
      acc[nt2] = __builtin_amdgcn_mfma_f32_16x16x32_bf16(a1, b1, acc[nt2], 0, 0, 0);
    }
    __syncthreads();
  }

  int row_base = m0 + w * 16 + quad * 4;

  if (MODE == 4) {
    int hh = row_base >> 4;       // 0..95
    float b0 = bias[row_base + 0], b1 = bias[row_base + 1];
    float b2 = bias[row_base + 2], b3 = bias[row_base + 3];
    if (hh < 32) {                // q (hh<16) or k
      unsigned short* qkout = (unsigned short*)outv + ((hh < 16) ? 0 : 2097152);
      float os = (hh < 16) ? QK_SC : 1.0f;
      int head = hh & 15, kd0 = row_base & 15;
      #pragma unroll
      for (int c = 0; c < 4; ++c) {
        int col = n0 + c * 16 + ml;
        uint2 pw;
        pw.x = f2b2((acc[c][0] + b0) * os, (acc[c][1] + b1) * os);
        pw.y = f2b2((acc[c][2] + b2) * os, (acc[c][3] + b3) * os);
        *(uint2*)&qkout[(((size_t)b * 16 + head) * 1024 + col) * 16 + kd0] = pw;
      }
    } else {                      // v: k-major [b][d][1024]
      unsigned short* vout = (unsigned short*)outv + 4194304;
      int d0 = row_base - 512;
      #pragma unroll
      for (int c = 0; c < 4; ++c) {
        int col = n0 + c * 16 + ml;
        vout[((size_t)b * 1024 + d0 + 0) * 1024 + col] = f2b(acc[c][0] + b0);
        vout[((size_t)b * 1024 + d0 + 1) * 1024 + col] = f2b(acc[c][1] + b1);
        vout[((size_t)b * 1024 + d0 + 2) * 1024 + col] = f2b(acc[c][2] + b2);
        vout[((size_t)b * 1024 + d0 + 3) * 1024 + col] = f2b(acc[c][3] + b3);
      }
    }
  } else if (MODE == 5) {          // proj -> xf1_t n-major bf16 + stats
    unsigned short* outp = (unsigned short*)outv;
    float vsum[4] = {0.f, 0.f, 0.f, 0.f}, vsq[4] = {0.f, 0.f, 0.f, 0.f};
    #pragma unroll
    for (int c = 0; c < 4; ++c) {
      int col = n0 + c * 16 + ml;
      float v0 = acc[c][0] + bias[row_base + 0] + resf[((size_t)b * 256 + row_base + 0) * 1024 + col];
      float v1 = acc[c][1] + bias[row_base + 1] + resf[((size_t)b * 256 + row_base + 1) * 1024 + col];
      float v2 = acc[c][2] + bias[row_base + 2] + resf[((size_t)b * 256 + row_base + 2) * 1024 + col];
      float v3 = acc[c][3] + bias[row_base + 3] + resf[((size_t)b * 256 + row_base + 3) * 1024 + col];
      vsum[0] += v0; vsq[0] += v0 * v0;
      vsum[1] += v1; vsq[1] += v1 * v1;
      vsum[2] += v2; vsq[2] += v2 * v2;
      vsum[3] += v3; vsq[3] += v3 * v3;
      uint2 pw; pw.x = f2b2(v0, v1); pw.y = f2b2(v2, v3);
      *(uint2*)&outp[((size_t)b * 1024 + col) * 256 + row_base] = pw;
    }
    #pragma unroll
    for (int r = 0; r < 4; ++r) {
      float s = vsum[r], q = vsq[r];
      #pragma unroll
      for (int o = 1; o < 16; o <<= 1) { s += __shfl_xor(s, o, 64); q += __shfl_xor(q, o, 64); }
      if (ml == 0) {
        atomicAdd(stats + row_base + r, s);
        atomicAdd(stats + 256 + row_base + r, q);
      }
    }
  } else if (MODE == 6) {          // MLP1 -> hb_t n-major bf16 + relu6
    unsigned short* outp = (unsigned short*)outv;
    #pragma unroll
    for (int c = 0; c < 4; ++c) {
      int col = n0 + c * 16 + ml;
      float v0 = fminf(fmaxf(acc[c][0] + bias[row_base + 0], 0.f), 6.f);
      float v1 = fminf(fmaxf(acc[c][1] + bias[row_base + 1], 0.f), 6.f);
      float v2 = fminf(fmaxf(acc[c][2] + bias[row_base + 2], 0.f), 6.f);
      float v3 = fminf(fmaxf(acc[c][3] + bias[row_base + 3], 0.f), 6.f);
      uint2 pw; pw.x = f2b2(v0, v1); pw.y = f2b2(v2, v3);
      *(uint2*)&outp[((size_t)b * 1024 + col) * 1024 + row_base] = pw;
    }
  } else {                          // MODE 7: MLP2 -> d_out f32 + res from xf1_t
    float* outp = (float*)outv;
    #pragma unroll
    for (int c = 0; c < 4; ++c) {
      int col = n0 + c * 16 + ml;
      uint2 rv = *(const uint2*)(resb + ((size_t)b * 1024 + col) * 256 + row_base);
      float r0 = b2f((unsigned short)(rv.x & 0xffff));
      float r1 = b2f((unsigned short)(rv.x >> 16));
      float r2 = b2f((unsigned short)(rv.y & 0xffff));
      float r3 = b2f((unsigned short)(rv.y >> 16));
      outp[((size_t)b * 256 + row_base + 0) * 1024 + col] = acc[c][0] + bias[row_base + 0] + r0;
      outp[((size_t)b * 256 + row_base + 1) * 1024 + col] = acc[c][1] + bias[row_base + 1] + r1;
      outp[((size_t)b * 256 + row_base + 2) * 1024 + col] = acc[c][2] + bias[row_base + 2] + r2;
      outp[((size_t)b * 256 + row_base + 3) * 1024 + col] = acc[c][3] + bias[row_base + 3] + r3;
    }
  }
}

// ---------------------------------------------------------------------------
// Attention R19: K/V double-buffered via global_load_lds (compiler cannot
// sink it; drain lands at end-of-iter barrier AFTER compute). Cooperative:
// wave w stages V rows w*16..+15 of tile i+1; wave 0 stages K (contiguous
// 1KB). V uses rule-#21 swizzle (src cg ^= row&3, read XOR same). Compute
// reads K/V frags via ds_read_b128 from buf. One barrier per iter.
// Pscr/softmax/PV/epilogue identical to proven R13 kernel.
// ---------------------------------------------------------------------------
__global__ __launch_bounds__(256, 4) void attn_kernel(
    const unsigned short* __restrict__ qt, const unsigned short* __restrict__ kt,
    const unsigned short* __restrict__ vt, unsigned short* __restrict__ ot) {
  int bx0 = blockIdx.x;
  int bx = (bx0 & 7) * 128 + (bx0 >> 3);   // bijective XCD grouping
  int nt = bx & 7, h = (bx >> 3) & 15, b = bx >> 7;
  int tid = threadIdx.x, lane = tid & 63, w = tid >> 6;
  int ml = lane & 15, quad = lane >> 4;

  __shared__ unsigned int Pscr[4][2][2][16][18];  // [wave][buf][rg][n][m-packed u32]
  __shared__ float Ssum[4][2][16];
  __shared__ unsigned short Kt[2][32][16];        // 2x1KB, linear
  __shared__ unsigned short Vt[2][64][32];        // 2x4KB, swizzled cols

  const int n0 = nt * 128 + w * 32;
  const size_t qk_row = ((size_t)b * 16 + h) * 1024;

  short8 qf[2];
  #pragma unroll
  for (int rg = 0; rg < 2; ++rg) {
    short8 z = {0, 0, 0, 0, 0, 0, 0, 0};
    if (quad < 2)
      z = *(const short8*)(qt + (qk_row + n0 + rg * 16 + ml) * 16 + quad * 8);
    qf[rg] = z;
  }

  const floatx4 zf = {0.f, 0.f, 0.f, 0.f};
  floatx4 oacc[2][4];
  #pragma unroll
  for (int rg = 0; rg < 2; ++rg)
    #pragma unroll
    for (int dt = 0; dt < 4; ++dt) oacc[rg][dt] = zf;
  float psum0 = 0.f, psum1 = 0.f;

  const unsigned short* kp = kt + qk_row * 16;
  const unsigned short* vp = vt + ((size_t)b * 1024 + h * 64) * 1024;

  // staging coords (V): wave w covers rows w*16..w*16+15 of the 64-row tile
  int vrow = w * 16 + (lane >> 2);          // per-lane V row (0..63)
  int vcg  = (lane & 3) ^ ((lane >> 2) & 3); // pre-swizzled source col-group

  auto stageKV = [&](int buf, int mc) {
    gload16(vp + (size_t)vrow * 1024 + mc + vcg * 8, &Vt[buf][w * 16][0]);
    if (w == 0)
      gload16(kp + (size_t)mc * 16 + lane * 8, &Kt[buf][0][0]);
  };

  // prologue: tile 0 staged
  stageKV(0, 0);
  __syncthreads();

  for (int it = 0; it < 32; ++it) {
    int buf = it & 1;
    int mc = it << 5;
    if (it < 31) stageKV(buf ^ 1, mc + 32);   // prefetch next tile

    // --- read K frags from LDS (linear; quad>=2 lanes are zero / K=16) ---
    const char* Kb = (const char*)&Kt[buf][0][0];
    const char* Vb = (const char*)&Vt[buf][0][0];
    const short8 z8 = {0, 0, 0, 0, 0, 0, 0, 0};
    short8 kf[2];
    #pragma unroll
    for (int tt = 0; tt < 2; ++tt)
      kf[tt] = (quad < 2) ? *(const short8*)(Kb + (tt * 16 + ml) * 32 + quad * 16) : z8;
    // --- read V frags (XOR-swizzled cols) ---
    short8 vf[4];
    #pragma unroll
    for (int dt = 0; dt < 4; ++dt)
      vf[dt] = *(const short8*)(Vb + (dt * 16 + ml) * 64 + ((quad ^ (ml & 3)) << 4));

    #pragma unroll
    for (int rg = 0; rg < 2; ++rg) {
      #pragma unroll
      for (int tt = 0; tt < 2; ++tt) {
        floatx4 s = __builtin_amdgcn_mfma_f32_16x16x32_bf16(kf[tt], qf[rg], zf, 0, 0, 0);
        float p0 = __builtin_amdgcn_exp2f(s[0]);
        float p1 = __builtin_amdgcn_exp2f(s[1]);
        float p2 = __builtin_amdgcn_exp2f(s[2]);
        float p3 = __builtin_amdgcn_exp2f(s[3]);
        if (rg == 0) psum0 += (p0 + p1) + (p2 + p3);
        else         psum1 += (p0 + p1) + (p2 + p3);
        uint2 pw; pw.x = f2b2(p0, p1); pw.y = f2b2(p2, p3);
        *(uint2*)&Pscr[w][buf][rg][ml][tt * 8 + quad * 2] = pw;
      }
    }
    #pragma unroll
    for (int rg = 0; rg < 2; ++rg) {
      uint2 a0 = *(const uint2*)&Pscr[w][buf][rg][ml][quad * 4];
      uint2 a1 = *(const uint2*)&Pscr[w][buf][rg][ml][quad * 4 + 2];
      union { uint4 u; short8 s; } cv;
      cv.u = make_uint4(a0.x, a0.y, a1.x, a1.y);
      short8 af = cv.s;
      #pragma unroll
      for (int dt = 0; dt < 4; ++dt)
        oacc[rg][dt] = __builtin_amdgcn_mfma_f32_16x16x32_bf16(af, vf[dt], oacc[rg][dt], 0, 0, 0);
    }
    __syncthreads();   // drains prefetch (vmcnt) + protects buf reuse
  }

  {
    float s0 = psum0;
    s0 += __shfl_xor(s0, 16, 64);
    s0 += __shfl_xor(s0, 32, 64);
    float s1 = psum1;
    s1 += __shfl_xor(s1, 16, 64);
    s1 += __shfl_xor(s1, 32, 64);
    if (lane < 16) { Ssum[w][0][ml] = s0; Ssum[w][1][ml] = s1; }
  }
  #pragma unroll
  for (int rg = 0; rg < 2; ++rg) {
    float4 sv = *(const float4*)&Ssum[w][rg][quad * 4];
    float inv0 = 1.0f / sv.x, inv1 = 1.0f / sv.y;
    float inv2 = 1.0f / sv.z, inv3 = 1.0f / sv.w;
    int nbase = n0 + rg * 16 + quad * 4;
    #pragma unroll
    for (int dt = 0; dt < 4; ++dt) {
      int dg = h * 64 + dt * 16 + ml;
      size_t obase = (((size_t)b << 10) + nbase) * 1024 + dg;
      ot[obase + 0 * 1024] = f2b(oacc[rg][dt][0] * inv0);
      ot[obase + 1 * 1024] = f2b(oacc[rg][dt][1] * inv1);
      ot[obase + 2 * 1024] = f2b(oacc[rg][dt][2] * inv2);
      ot[obase + 3 * 1024] = f2b(oacc[rg][dt][3] * inv3);
    }
  }
}

// ---------------------------------------------------------------------------
extern "C" void kernel_launch(void* const* d_in, const int* in_sizes, int n_in,
                              void* d_out, int out_size, void* d_ws, size_t ws_size,
                              hipStream_t stream) {
  const float* x   = (const float*)d_in[0];
  const float* g1  = (const float*)d_in[1];
  const float* b1  = (const float*)d_in[2];
  const float* wq  = (const float*)d_in[3];
  const float* bq  = (const float*)d_in[4];
  const float* wk  = (const float*)d_in[5];
  const float* bk  = (const float*)d_in[6];
  const float* wv  = (const float*)d_in[7];
  const float* bv  = (const float*)d_in[8];
  const float* wp  = (const float*)d_in[9];
  const float* bp  = (const float*)d_in[10];
  const float* g2  = (const float*)d_in[11];
  const float* b2  = (const float*)d_in[12];
  const float* w1  = (const float*)d_in[13];
  const float* bb1 = (const float*)d_in[14];
  const float* w2  = (const float*)d_in[15];
  const float* bb2 = (const float*)d_in[16];

  char* ws = (char*)d_ws;
  float* bnacc   = (float*)ws;                  // 1024 f: sum1,sq1 | sum2,sq2
  float* biasqkv = (float*)(ws + 4096);         // 1536 f
  unsigned short* y_t  = (unsigned short*)(ws + 16384);    // bf16 [8][1024][256]
  unsigned short* qt   = y_t + (size_t)2 * 1024 * 1024;    // bf16 [8][16][1024][16]
  unsigned short* kt   = qt  + (size_t)2 * 1024 * 1024;    // = qt + 2097152
  unsigned short* vt   = kt  + (size_t)2 * 1024 * 1024;    // = qt + 4194304
  unsigned short* ot   = vt  + (size_t)8 * 1024 * 1024;    // bf16 [8][1024][1024] n-major
  unsigned short* xf1t = ot  + (size_t)8 * 1024 * 1024;    // bf16 [8][1024][256] n-major
  unsigned short* wb   = xf1t + (size_t)2 * 1024 * 1024;
  unsigned short* hb_t = ot;          // reuse: ot dead after proj
  float* outp = (float*)d_out;

  unsigned short* wqkvb = wb;         // rows 0..255 wq | 256..511 wk | 512..1535 wv
  unsigned short* wpb = wb + 393216;
  unsigned short* w1b = wb + 655360;
  unsigned short* w2b = wb + 917504;
  const unsigned short* nub = nullptr;
  const float* nuf = nullptr;

  hipMemsetAsync(bnacc, 0, 4096, stream);
  prep<<<dim3(3206), dim3(256), 0, stream>>>(
      wq, wk, wv, wp, w1, w2, wb, x, bnacc, bq, bk, bv, biasqkv);

  // --- attention branch ---
  bn_apply_t<<<dim3(16, 4, 8), dim3(256), 0, stream>>>(x, bnacc, g1, b1, y_t);
  gemm3<4><<<dim3(3072), dim3(256), 0, stream>>>(
      wqkvb, y_t, biasqkv, nuf, nub, qt, nullptr, nuf, nuf, nuf, 1536, 256);
  attn_kernel<<<dim3(1024), dim3(256), 0, stream>>>(qt, kt, vt, ot);
  gemm3<5><<<dim3(512), dim3(256), 0, stream>>>(
      wpb, ot, bp, x, nub, xf1t, bnacc + 512, nuf, nuf, nuf, 256, 1024);

  // --- MLP branch ---
  gemm3<6><<<dim3(2048), dim3(256), 0, stream>>>(
      w1b, xf1t, bb1, nuf, nub, hb_t, nullptr, bnacc + 512, g2, b2, 1024, 256);
  gemm3<7><<<dim3(512), dim3(256), 0, stream>>>(
      w2b, hb_t, bb2, nuf, xf1t, outp, nullptr, nuf, nuf, nuf, 256, 1024);
}

// Round 8
// 202.467 us; speedup vs baseline: 1.2651x; 1.0307x over previous
//
#include <hip/hip_runtime.h>
#include <hip/hip_bf16.h>
#include <cstdint>

// ---------------------------------------------------------------------------
// TextBlock: BN -> {q,k,v} -> MHSA (NH=16, KD=16, D=64, N=1024) -> proj -> +res
//            -> BN -> MLP(1024, relu6) -> +res.   B=8, C=256.
// I/O FLOAT32. Intermediates bf16 for MFMA, fp32 accumulation.
// R16 WIN: gemm gload_lds w16 + both-sides XOR swizzle.
// R19 WIN (208.7us): attn K/V double-buffered gload_lds staging (attn 76->44).
//      NOTE: ~90us of measured time is harness fillBufferAligned (268MB
//      workspace re-poison x2) - fixed overhead, not ours.
// R20: (a) attn V-read bank fix: old swz quad^(ml&3) left ml vs ml+4 on the
//      same bank (row stride 64B=16 banks -> bank sees only row&1; ml&3 has
//      period 4) = 4-way conflict, 2.1M counted. New basis (row>>1)&3:
//      source (l&3)^((l>>3)&3), read quad^((ml>>1)&3) -> free 2-way.
//      (b) gemm TM=128 for modes 4,6 (M=1536/1024): per-wave 32x64 out,
//      16 MFMA / 12 ds_read (was 8/10) - halves B-frag duplication across
//      waves. Modes 5,7 (M=256) keep TM=64 (occupancy). Same swizzle algebra
//      (only row&7 enters; preserved for any TM mult of 64).
// ---------------------------------------------------------------------------

typedef __attribute__((ext_vector_type(8))) short short8;
typedef __attribute__((ext_vector_type(4))) float floatx4;

#define QK_SC 5.770780163555851f   // sqrt(kd)=4 times log2(e), folded into Q

__device__ __forceinline__ float b2f(unsigned short u) {
  union { unsigned int i; float f; } x; x.i = ((unsigned int)u) << 16; return x.f;
}
__device__ __forceinline__ unsigned short f2b(float f) {
  union { float f; unsigned int i; } x; x.f = f;
  unsigned int r = x.i + 0x7FFFu + ((x.i >> 16) & 1u);   // RNE
  return (unsigned short)(r >> 16);
}
// packed f32x2 -> bf16x2 (v_cvt_pk_bf16_f32 on gfx950)
__device__ __forceinline__ unsigned int f2b2(float a, float b) {
  __hip_bfloat162 h = __float22bfloat162_rn(make_float2(a, b));
  union { __hip_bfloat162 v; unsigned int u; } x; x.v = h; return x.u;
}
// async global->LDS, 16B per lane; LDS dest is wave-uniform base + lane*16.
__device__ __forceinline__ void gload16(const unsigned short* g, unsigned short* l) {
  __builtin_amdgcn_global_load_lds(
      (const __attribute__((address_space(1))) unsigned int*)g,
      (__attribute__((address_space(3))) unsigned int*)l, 16, 0, 0);
}

// ---------------------------------------------------------------------------
// prep: blocks 0..1151 convert the 6 weight mats f32->bf16 into wb;
//       blocks 1152..3199 accumulate BN1 partial sums of x into bnacc;
//       blocks 3200..3205 concat bq|bk|bv into biasqkv.
// ---------------------------------------------------------------------------
__global__ __launch_bounds__(256) void prep(
    const float* __restrict__ s0, const float* __restrict__ s1,
    const float* __restrict__ s2, const float* __restrict__ s3,
    const float* __restrict__ s4, const float* __restrict__ s5,
    unsigned short* __restrict__ dst,
    const float* __restrict__ x, float* __restrict__ acc,
    const float* __restrict__ bq, const float* __restrict__ bk,
    const float* __restrict__ bv, float* __restrict__ biasqkv) {
  int blk = blockIdx.x, t = threadIdx.x;
  if (blk < 1152) {
    int i = blk * 256 + t;   // float4-group index
    if (i >= 294912) return;
    const float* s; int li; size_t dbase;
    if (i < 16384)       { s = s0; li = i;          dbase = 0; }
    else if (i < 32768)  { s = s1; li = i - 16384;  dbase = 65536; }
    else if (i < 98304)  { s = s2; li = i - 32768;  dbase = 131072; }
    else if (i < 163840) { s = s3; li = i - 98304;  dbase = 393216; }
    else if (i < 229376) { s = s4; li = i - 163840; dbase = 655360; }
    else                 { s = s5; li = i - 229376; dbase = 917504; }
    float4 v = ((const float4*)s)[li];
    uint2 o; o.x = f2b2(v.x, v.y); o.y = f2b2(v.z, v.w);
    ((uint2*)(dst + dbase))[li] = o;
  } else if (blk < 3200) {
    int blk2 = blk - 1152;
    int b = blk2 >> 8, c = blk2 & 255;
    const float* p = x + (((size_t)(b * 256 + c)) << 10);
    float4 v = ((const float4*)p)[t];
    float s = (v.x + v.y) + (v.z + v.w);
    float s2 = (v.x * v.x + v.y * v.y) + (v.z * v.z + v.w * v.w);
    #pragma unroll
    for (int o = 32; o > 0; o >>= 1) { s += __shfl_down(s, o, 64); s2 += __shfl_down(s2, o, 64); }
    __shared__ float rs[4], rs2[4];
    int w = t >> 6;
    if ((t & 63) == 0) { rs[w] = s; rs2[w] = s2; }
    __syncthreads();
    if (t == 0) {
      atomicAdd(acc + c, (rs[0] + rs[1]) + (rs[2] + rs[3]));
      atomicAdd(acc + 256 + c, (rs2[0] + rs2[1]) + (rs2[2] + rs2[3]));
    }
  } else {
    int i = (blk - 3200) * 256 + t;   // 0..1535
    float v = (i < 256) ? bq[i] : (i < 512) ? bk[i - 256] : bv[i - 512];
    biasqkv[i] = v;
  }
}

// ---------------------------------------------------------------------------
// BN apply + transpose (finalize fused): x[b][c][n] f32 -> y_t[b][n][c] bf16.
// ---------------------------------------------------------------------------
__global__ __launch_bounds__(256) void bn_apply_t(
    const float* __restrict__ x, const float* __restrict__ acc,
    const float* __restrict__ g, const float* __restrict__ bb,
    unsigned short* __restrict__ yt) {
  int nt = blockIdx.x, ct = blockIdx.y, b = blockIdx.z;
  int t = threadIdx.x;
  __shared__ unsigned short T[64][72];
  {
    int r = t >> 2, g4 = (t & 3) * 16;
    int c = ct * 64 + r;
    float m = acc[c] * (1.0f / 8192.0f);
    float var = acc[256 + c] * (1.0f / 8192.0f) - m * m;
    float scl = g[c] * rsqrtf(var + 1e-5f);
    float shf = bb[c] - m * scl;
    const float* p = x + (((size_t)(b * 256 + c)) << 10) + nt * 64 + g4;
    float4 u0 = *(const float4*)(p);
    float4 u1 = *(const float4*)(p + 4);
    float4 u2 = *(const float4*)(p + 8);
    float4 u3 = *(const float4*)(p + 12);
    uint4 o0, o1;
    o0.x = f2b2(fmaf(u0.x, scl, shf), fmaf(u0.y, scl, shf));
    o0.y = f2b2(fmaf(u0.z, scl, shf), fmaf(u0.w, scl, shf));
    o0.z = f2b2(fmaf(u1.x, scl, shf), fmaf(u1.y, scl, shf));
    o0.w = f2b2(fmaf(u1.z, scl, shf), fmaf(u1.w, scl, shf));
    o1.x = f2b2(fmaf(u2.x, scl, shf), fmaf(u2.y, scl, shf));
    o1.y = f2b2(fmaf(u2.z, scl, shf), fmaf(u2.w, scl, shf));
    o1.z = f2b2(fmaf(u3.x, scl, shf), fmaf(u3.y, scl, shf));
    o1.w = f2b2(fmaf(u3.z, scl, shf), fmaf(u3.w, scl, shf));
    *(uint4*)&T[r][g4] = o0;
    *(uint4*)&T[r][g4 + 8] = o1;
  }
  __syncthreads();
  {
    int nr = t >> 2, cg = (t & 3) * 16;
    unsigned int ob[8];
    #pragma unroll
    for (int j = 0; j < 8; ++j) {
      unsigned int lo = T[cg + 2 * j][nr];
      unsigned int hi = T[cg + 2 * j + 1][nr];
      ob[j] = lo | (hi << 16);
    }
    unsigned short* orow = yt + ((size_t)(b * 1024 + nt * 64 + nr)) * 256 + ct * 64 + cg;
    *(uint4*)&orow[0] = make_uint4(ob[0], ob[1], ob[2], ob[3]);
    *(uint4*)&orow[8] = make_uint4(ob[4], ob[5], ob[6], ob[7]);
  }
}

// ---------------------------------------------------------------------------
// MFMA GEMM (TMx64 tile, BK=64, (256,4)):  out = W[M,K] @ Bn_b[N,K]^T + bias
// R16 staging: global_load_lds w16 into UNPADDED LDS, both-sides XOR swizzle
// ((cg ^ (row&7))<<4). TM=128 (modes 4,6): wave computes 32x64 (2 rowgroups),
// 16 MFMA / 12 ds_read. TM=64 (modes 5,7): wave computes 16x64 (proven R16).
// ---------------------------------------------------------------------------
template <int MODE, int TM>
__global__ __launch_bounds__(256, 4) void gemm3(
    const unsigned short* __restrict__ W, const unsigned short* __restrict__ Bn,
    const float* __restrict__ bias, const float* __restrict__ resf,
    const unsigned short* __restrict__ resb, void* __restrict__ outv,
    float* __restrict__ stats, const float* __restrict__ bnin,
    const float* __restrict__ g, const float* __restrict__ bb, int M, int K) {
  constexpr int RG = TM / 64;     // rowgroups per wave
  constexpr int WR = TM / 4;      // rows per wave
  int bid = blockIdx.x;
  int b = bid & 7;                 // XCD-grouped: each XCD owns one batch
  int rest = bid >> 3;
  int n0 = (rest & 15) * 64, m0 = (rest >> 4) * TM;
  int t = threadIdx.x, lane = t & 63, w = t >> 6;
  int ml = lane & 15, quad = lane >> 4;

  __shared__ unsigned short Wt[TM][64];
  __shared__ unsigned short Yt[64][64];
  __shared__ float Scl[256], Shf[256];

  if (MODE == 6) {   // precompute BN2 scale/shift (c = t)
    float m = bnin[t] * (1.0f / 8192.0f);
    float var = bnin[256 + t] * (1.0f / 8192.0f) - m * m;
    float scl = g[t] * rsqrtf(var + 1e-5f);
    Scl[t] = scl;
    Shf[t] = bb[t] - m * scl;
    __syncthreads();
  }

  const unsigned short* Bp = Bn + (size_t)b * 1024 * K;
  int sr = t >> 2, scg = (t & 3) * 16;                 // mode-6 B staging coords
  const unsigned short* brow = Bp + (size_t)(n0 + sr) * K + scg;

  // gload staging coords (per wave-call of 8 rows)
  int lrow = lane >> 3;                 // 0..7 within call
  int cgs  = (lane & 7) ^ lrow;         // pre-swizzled source col-group

  char* Wb = (char*)&Wt[0][0];
  char* Yb = (char*)&Yt[0][0];
  const int swa = (ml & 7) << 4;        // read-side XOR byte mask

  floatx4 acc[RG][4];
  #pragma unroll
  for (int rg = 0; rg < RG; ++rg)
    #pragma unroll
    for (int i = 0; i < 4; ++i) acc[rg][i] = (floatx4){0.f, 0.f, 0.f, 0.f};

  for (int k0 = 0; k0 < K; k0 += 64) {
    // --- stage W tile: WR/8 gload calls/wave (8 rows each) ---
    #pragma unroll
    for (int j = 0; j < WR / 8; ++j) {
      int row = w * WR + j * 8 + lrow;
      gload16(W + (size_t)(m0 + row) * K + k0 + cgs * 8, &Wt[w * WR + j * 8][0]);
    }
    if (MODE == 6) {   // BN2-apply inline: y2 = xf1*scl + shf -> swizzled store
      uint4 r0 = *(const uint4*)(brow + k0);
      uint4 r1 = *(const uint4*)(brow + k0 + 8);
      int cb = k0 + scg;
      float4 s0 = *(const float4*)&Scl[cb],     h0 = *(const float4*)&Shf[cb];
      float4 s1 = *(const float4*)&Scl[cb + 4], h1 = *(const float4*)&Shf[cb + 4];
      float4 s2 = *(const float4*)&Scl[cb + 8], h2 = *(const float4*)&Shf[cb + 8];
      float4 s3 = *(const float4*)&Scl[cb + 12], h3 = *(const float4*)&Shf[cb + 12];
      uint4 o0, o1;
      o0.x = f2b2(fmaf(b2f(r0.x & 0xffff), s0.x, h0.x), fmaf(b2f(r0.x >> 16), s0.y, h0.y));
      o0.y = f2b2(fmaf(b2f(r0.y & 0xffff), s0.z, h0.z), fmaf(b2f(r0.y >> 16), s0.w, h0.w));
      o0.z = f2b2(fmaf(b2f(r0.z & 0xffff), s1.x, h1.x), fmaf(b2f(r0.z >> 16), s1.y, h1.y));
      o0.w = f2b2(fmaf(b2f(r0.w & 0xffff), s1.z, h1.z), fmaf(b2f(r0.w >> 16), s1.w, h1.w));
      o1.x = f2b2(fmaf(b2f(r1.x & 0xffff), s2.x, h2.x), fmaf(b2f(r1.x >> 16), s2.y, h2.y));
      o1.y = f2b2(fmaf(b2f(r1.y & 0xffff), s2.z, h2.z), fmaf(b2f(r1.y >> 16), s2.w, h2.w));
      o1.z = f2b2(fmaf(b2f(r1.z & 0xffff), s3.x, h3.x), fmaf(b2f(r1.z >> 16), s3.y, h3.y));
      o1.w = f2b2(fmaf(b2f(r1.w & 0xffff), s3.z, h3.z), fmaf(b2f(r1.w >> 16), s3.w, h3.w));
      int sg0 = (t & 3) * 2, sg1 = sg0 + 1;           // logical 8-short groups
      *(uint4*)(Yb + sr * 128 + ((sg0 ^ (sr & 7)) << 4)) = o0;
      *(uint4*)(Yb + sr * 128 + ((sg1 ^ (sr & 7)) << 4)) = o1;
    } else {
      // --- stage B tile via gload, same pre-swizzle ---
      #pragma unroll
      for (int j = 0; j < 2; ++j) {
        int row = w * 16 + j * 8 + lrow;
        gload16(Bp + (size_t)(n0 + row) * K + k0 + cgs * 8, &Yt[w * 16 + j * 8][0]);
      }
    }
    __syncthreads();
    short8 a0[RG], a1[RG];
    #pragma unroll
    for (int rg = 0; rg < RG; ++rg) {
      int arow = w * WR + rg * 16 + ml;
      a0[rg] = *(const short8*)(Wb + arow * 128 + ((quad << 4) ^ swa));
      a1[rg] = *(const short8*)(Wb + arow * 128 + (((quad + 4) << 4) ^ swa));
    }
    #pragma unroll
    for (int nt2 = 0; nt2 < 4; ++nt2) {
      int brw = nt2 * 16 + ml;
      short8 b0 = *(const short8*)(Yb + brw * 128 + ((quad << 4) ^ swa));
      short8 b1 = *(const short8*)(Yb + brw * 128 + (((quad + 4) << 4) ^ swa));
      #pragma unroll
      for (int rg = 0; rg < RG; ++rg) {
        acc[rg][nt2] = __builtin_amdgcn_mfma_f32_16x16x32_bf16(a0[rg], b0, acc[rg][nt2], 0, 0, 0);
        acc[rg][nt2] = __builtin_amdgcn_mfma_f32_16x16x32_bf16(a1[rg], b1, acc[rg][nt2], 0, 0, 0);
      }
    }
    __syncthreads();
  }

  #pragma unroll
  for (int rg = 0; rg < RG; ++rg) {
    int row_base = m0 + w * WR + rg * 16 + quad * 4;

    if (MODE == 4) {
      int hh = row_base >> 4;       // 0..95
      float b0 = bias[row_base + 0], b1 = bias[row_base + 1];
      float b2 = bias[row_base + 2], b3 = bias[row_base + 3];
      if (hh < 32) {                // q (hh<16) or k
        unsigned short* qkout = (unsigned short*)outv + ((hh < 16) ? 0 : 2097152);
        float os = (hh < 16) ? QK_SC : 1.0f;
        int head = hh & 15, kd0 = row_base & 15;
        #pragma unroll
        for (int c = 0; c < 4; ++c) {
          int col = n0 + c * 16 + ml;
          uint2 pw;
          pw.x = f2b2((acc[rg][c][0] + b0) * os, (acc[rg][c][1] + b1) * os);
          pw.y = f2b2((acc[rg][c][2] + b2) * os, (acc[rg][c][3] + b3) * os);
          *(uint2*)&qkout[(((size_t)b * 16 + head) * 1024 + col) * 16 + kd0] = pw;
        }
      } else {                      // v: k-major [b][d][1024]
        unsigned short* vout = (unsigned short*)outv + 4194304;
        int d0 = row_base - 512;
        #pragma unroll
        for (int c = 0; c < 4; ++c) {
          int col = n0 + c * 16 + ml;
          vout[((size_t)b * 1024 + d0 + 0) * 1024 + col] = f2b(acc[rg][c][0] + b0);
          vout[((size_t)b * 1024 + d0 + 1) * 1024 + col] = f2b(acc[rg][c][1] + b1);
          vout[((size_t)b * 1024 + d0 + 2) * 1024 + col] = f2b(acc[rg][c][2] + b2);
          vout[((size_t)b * 1024 + d0 + 3) * 1024 + col] = f2b(acc[rg][c][3] + b3);
        }
      }
    } else if (MODE == 5) {          // proj -> xf1_t n-major bf16 + stats
      unsigned short* outp = (unsigned short*)outv;
      float vsum[4] = {0.f, 0.f, 0.f, 0.f}, vsq[4] = {0.f, 0.f, 0.f, 0.f};
      #pragma unroll
      for (int c = 0; c < 4; ++c) {
        int col = n0 + c * 16 + ml;
        float v0 = acc[rg][c][0] + bias[row_base + 0] + resf[((size_t)b * 256 + row_base + 0) * 1024 + col];
        float v1 = acc[rg][c][1] + bias[row_base + 1] + resf[((size_t)b * 256 + row_base + 1) * 1024 + col];
        float v2 = acc[rg][c][2] + bias[row_base + 2] + resf[((size_t)b * 256 + row_base + 2) * 1024 + col];
        float v3 = acc[rg][c][3] + bias[row_base + 3] + resf[((size_t)b * 256 + row_base + 3) * 1024 + col];
        vsum[0] += v0; vsq[0] += v0 * v0;
        vsum[1] += v1; vsq[1] += v1 * v1;
        vsum[2] += v2; vsq[2] += v2 * v2;
        vsum[3] += v3; vsq[3] += v3 * v3;
        uint2 pw; pw.x = f2b2(v0, v1); pw.y = f2b2(v2, v3);
        *(uint2*)&outp[((size_t)b * 1024 + col) * 256 + row_base] = pw;
      }
      #pragma unroll
      for (int r = 0; r < 4; ++r) {
        float s = vsum[r], q = vsq[r];
        #pragma unroll
        for (int o = 1; o < 16; o <<= 1) { s += __shfl_xor(s, o, 64); q += __shfl_xor(q, o, 64); }
        if (ml == 0) {
          atomicAdd(stats + row_base + r, s);
          atomicAdd(stats + 256 + row_base + r, q);
        }
      }
    } else if (MODE == 6) {          // MLP1 -> hb_t n-major bf16 + relu6
      unsigned short* outp = (unsigned short*)outv;
      #pragma unroll
      for (int c = 0; c < 4; ++c) {
        int col = n0 + c * 16 + ml;
        float v0 = fminf(fmaxf(acc[rg][c][0] + bias[row_base + 0], 0.f), 6.f);
        float v1 = fminf(fmaxf(acc[rg][c][1] + bias[row_base + 1], 0.f), 6.f);
        float v2 = fminf(fmaxf(acc[rg][c][2] + bias[row_base + 2], 0.f), 6.f);
        float v3 = fminf(fmaxf(acc[rg][c][3] + bias[row_base + 3], 0.f), 6.f);
        uint2 pw; pw.x = f2b2(v0, v1); pw.y = f2b2(v2, v3);
        *(uint2*)&outp[((size_t)b * 1024 + col) * 1024 + row_base] = pw;
      }
    } else {                          // MODE 7: MLP2 -> d_out f32 + res from xf1_t
      float* outp = (float*)outv;
      #pragma unroll
      for (int c = 0; c < 4; ++c) {
        int col = n0 + c * 16 + ml;
        uint2 rv = *(const uint2*)(resb + ((size_t)b * 1024 + col) * 256 + row_base);
        float r0 = b2f((unsigned short)(rv.x & 0xffff));
        float r1 = b2f((unsigned short)(rv.x >> 16));
        float r2 = b2f((unsigned short)(rv.y & 0xffff));
        float r3 = b2f((unsigned short)(rv.y >> 16));
        outp[((size_t)b * 256 + row_base + 0) * 1024 + col] = acc[rg][c][0] + bias[row_base + 0] + r0;
        outp[((size_t)b * 256 + row_base + 1) * 1024 + col] = acc[rg][c][1] + bias[row_base + 1] + r1;
        outp[((size_t)b * 256 + row_base + 2) * 1024 + col] = acc[rg][c][2] + bias[row_base + 2] + r2;
        outp[((size_t)b * 256 + row_base + 3) * 1024 + col] = acc[rg][c][3] + bias[row_base + 3] + r3;
      }
    }
  }
}

// ---------------------------------------------------------------------------
// Attention R19+R20a: K/V double-buffered via global_load_lds; V swizzle on
// (row>>1)&3 basis (free 2-way banks). One barrier/iter. 4 waves, (256,4).
// ---------------------------------------------------------------------------
__global__ __launch_bounds__(256, 4) void attn_kernel(
    const unsigned short* __restrict__ qt, const unsigned short* __restrict__ kt,
    const unsigned short* __restrict__ vt, unsigned short* __restrict__ ot) {
  int bx0 = blockIdx.x;
  int bx = (bx0 & 7) * 128 + (bx0 >> 3);   // bijective XCD grouping
  int nt = bx & 7, h = (bx >> 3) & 15, b = bx >> 7;
  int tid = threadIdx.x, lane = tid & 63, w = tid >> 6;
  int ml = lane & 15, quad = lane >> 4;

  __shared__ unsigned int Pscr[4][2][2][16][18];  // [wave][buf][rg][n][m-packed u32]
  __shared__ float Ssum[4][2][16];
  __shared__ unsigned short Kt[2][32][16];        // 2x1KB, linear
  __shared__ unsigned short Vt[2][64][32];        // 2x4KB, swizzled cols

  const int n0 = nt * 128 + w * 32;
  const size_t qk_row = ((size_t)b * 16 + h) * 1024;

  short8 qf[2];
  #pragma unroll
  for (int rg = 0; rg < 2; ++rg) {
    short8 z = {0, 0, 0, 0, 0, 0, 0, 0};
    if (quad < 2)
      z = *(const short8*)(qt + (qk_row + n0 + rg * 16 + ml) * 16 + quad * 8);
    qf[rg] = z;
  }

  const floatx4 zf = {0.f, 0.f, 0.f, 0.f};
  floatx4 oacc[2][4];
  #pragma unroll
  for (int rg = 0; rg < 2; ++rg)
    #pragma unroll
    for (int dt = 0; dt < 4; ++dt) oacc[rg][dt] = zf;
  float psum0 = 0.f, psum1 = 0.f;

  const unsigned short* kp = kt + qk_row * 16;
  const unsigned short* vp = vt + ((size_t)b * 1024 + h * 64) * 1024;

  // staging coords (V): wave w covers rows w*16..w*16+15 of the 64-row tile.
  // Swizzle basis (row>>1)&3: source cg = (l&3) ^ ((l>>3)&3).
  int vrow = w * 16 + (lane >> 2);           // per-lane V row (0..63)
  int vcg  = (lane & 3) ^ ((lane >> 3) & 3); // pre-swizzled source col-group

  auto stageKV = [&](int buf, int mc) {
    gload16(vp + (size_t)vrow * 1024 + mc + vcg * 8, &Vt[buf][w * 16][0]);
    if (w == 0)
      gload16(kp + (size_t)mc * 16 + lane * 8, &Kt[buf][0][0]);
  };

  // prologue: tile 0 staged
  stageKV(0, 0);
  __syncthreads();

  for (int it = 0; it < 32; ++it) {
    int buf = it & 1;
    int mc = it << 5;
    if (it < 31) stageKV(buf ^ 1, mc + 32);   // prefetch next tile

    // --- read K frags from LDS (linear; quad>=2 lanes are zero / K=16) ---
    const char* Kb = (const char*)&Kt[buf][0][0];
    const char* Vb = (const char*)&Vt[buf][0][0];
    const short8 z8 = {0, 0, 0, 0, 0, 0, 0, 0};
    short8 kf[2];
    #pragma unroll
    for (int tt = 0; tt < 2; ++tt)
      kf[tt] = (quad < 2) ? *(const short8*)(Kb + (tt * 16 + ml) * 32 + quad * 16) : z8;
    // --- read V frags (XOR-swizzled cols, (row>>1)&3 basis) ---
    short8 vf[4];
    #pragma unroll
    for (int dt = 0; dt < 4; ++dt)
      vf[dt] = *(const short8*)(Vb + (dt * 16 + ml) * 64 + ((quad ^ ((ml >> 1) & 3)) << 4));

    #pragma unroll
    for (int rg = 0; rg < 2; ++rg) {
      #pragma unroll
      for (int tt = 0; tt < 2; ++tt) {
        floatx4 s = __builtin_amdgcn_mfma_f32_16x16x32_bf16(kf[tt], qf[rg], zf, 0, 0, 0);
        float p0 = __builtin_amdgcn_exp2f(s[0]);
        float p1 = __builtin_amdgcn_exp2f(s[1]);
        float p2 = __builtin_amdgcn_exp2f(s[2]);
        float p3 = __builtin_amdgcn_exp2f(s[3]);
        if (rg == 0) psum0 += (p0 + p1) + (p2 + p3);
        else         psum1 += (p0 + p1) + (p2 + p3);
        uint2 pw; pw.x = f2b2(p0, p1); pw.y = f2b2(p2, p3);
        *(uint2*)&Pscr[w][buf][rg][ml][tt * 8 + quad * 2] = pw;
      }
    }
    #pragma unroll
    for (int rg = 0; rg < 2; ++rg) {
      uint2 a0 = *(const uint2*)&Pscr[w][buf][rg][ml][quad * 4];
      uint2 a1 = *(const uint2*)&Pscr[w][buf][rg][ml][quad * 4 + 2];
      union { uint4 u; short8 s; } cv;
      cv.u = make_uint4(a0.x, a0.y, a1.x, a1.y);
      short8 af = cv.s;
      #pragma unroll
      for (int dt = 0; dt < 4; ++dt)
        oacc[rg][dt] = __builtin_amdgcn_mfma_f32_16x16x32_bf16(af, vf[dt], oacc[rg][dt], 0, 0, 0);
    }
    __syncthreads();   // drains prefetch (vmcnt) + protects buf reuse
  }

  {
    float s0 = psum0;
    s0 += __shfl_xor(s0, 16, 64);
    s0 += __shfl_xor(s0, 32, 64);
    float s1 = psum1;
    s1 += __shfl_xor(s1, 16, 64);
    s1 += __shfl_xor(s1, 32, 64);
    if (lane < 16) { Ssum[w][0][ml] = s0; Ssum[w][1][ml] = s1; }
  }
  #pragma unroll
  for (int rg = 0; rg < 2; ++rg) {
    float4 sv = *(const float4*)&Ssum[w][rg][quad * 4];
    float inv0 = 1.0f / sv.x, inv1 = 1.0f / sv.y;
    float inv2 = 1.0f / sv.z, inv3 = 1.0f / sv.w;
    int nbase = n0 + rg * 16 + quad * 4;
    #pragma unroll
    for (int dt = 0; dt < 4; ++dt) {
      int dg = h * 64 + dt * 16 + ml;
      size_t obase = (((size_t)b << 10) + nbase) * 1024 + dg;
      ot[obase + 0 * 1024] = f2b(oacc[rg][dt][0] * inv0);
      ot[obase + 1 * 1024] = f2b(oacc[rg][dt][1] * inv1);
      ot[obase + 2 * 1024] = f2b(oacc[rg][dt][2] * inv2);
      ot[obase + 3 * 1024] = f2b(oacc[rg][dt][3] * inv3);
    }
  }
}

// ---------------------------------------------------------------------------
extern "C" void kernel_launch(void* const* d_in, const int* in_sizes, int n_in,
                              void* d_out, int out_size, void* d_ws, size_t ws_size,
                              hipStream_t stream) {
  const float* x   = (const float*)d_in[0];
  const float* g1  = (const float*)d_in[1];
  const float* b1  = (const float*)d_in[2];
  const float* wq  = (const float*)d_in[3];
  const float* bq  = (const float*)d_in[4];
  const float* wk  = (const float*)d_in[5];
  const float* bk  = (const float*)d_in[6];
  const float* wv  = (const float*)d_in[7];
  const float* bv  = (const float*)d_in[8];
  const float* wp  = (const float*)d_in[9];
  const float* bp  = (const float*)d_in[10];
  const float* g2  = (const float*)d_in[11];
  const float* b2  = (const float*)d_in[12];
  const float* w1  = (const float*)d_in[13];
  const float* bb1 = (const float*)d_in[14];
  const float* w2  = (const float*)d_in[15];
  const float* bb2 = (const float*)d_in[16];

  char* ws = (char*)d_ws;
  float* bnacc   = (float*)ws;                  // 1024 f: sum1,sq1 | sum2,sq2
  float* biasqkv = (float*)(ws + 4096);         // 1536 f
  unsigned short* y_t  = (unsigned short*)(ws + 16384);    // bf16 [8][1024][256]
  unsigned short* qt   = y_t + (size_t)2 * 1024 * 1024;    // bf16 [8][16][1024][16]
  unsigned short* kt   = qt  + (size_t)2 * 1024 * 1024;    // = qt + 2097152
  unsigned short* vt   = kt  + (size_t)2 * 1024 * 1024;    // = qt + 4194304
  unsigned short* ot   = vt  + (size_t)8 * 1024 * 1024;    // bf16 [8][1024][1024] n-major
  unsigned short* xf1t = ot  + (size_t)8 * 1024 * 1024;    // bf16 [8][1024][256] n-major
  unsigned short* wb   = xf1t + (size_t)2 * 1024 * 1024;
  unsigned short* hb_t = ot;          // reuse: ot dead after proj
  float* outp = (float*)d_out;

  unsigned short* wqkvb = wb;         // rows 0..255 wq | 256..511 wk | 512..1535 wv
  unsigned short* wpb = wb + 393216;
  unsigned short* w1b = wb + 655360;
  unsigned short* w2b = wb + 917504;
  const unsigned short* nub = nullptr;
  const float* nuf = nullptr;

  hipMemsetAsync(bnacc, 0, 4096, stream);
  prep<<<dim3(3206), dim3(256), 0, stream>>>(
      wq, wk, wv, wp, w1, w2, wb, x, bnacc, bq, bk, bv, biasqkv);

  // --- attention branch ---
  bn_apply_t<<<dim3(16, 4, 8), dim3(256), 0, stream>>>(x, bnacc, g1, b1, y_t);
  gemm3<4, 128><<<dim3(1536), dim3(256), 0, stream>>>(
      wqkvb, y_t, biasqkv, nuf, nub, qt, nullptr, nuf, nuf, nuf, 1536, 256);
  attn_kernel<<<dim3(1024), dim3(256), 0, stream>>>(qt, kt, vt, ot);
  gemm3<5, 64><<<dim3(512), dim3(256), 0, stream>>>(
      wpb, ot, bp, x, nub, xf1t, bnacc + 512, nuf, nuf, nuf, 256, 1024);

  // --- MLP branch ---
  gemm3<6, 128><<<dim3(1024), dim3(256), 0, stream>>>(
      w1b, xf1t, bb1, nuf, nub, hb_t, nullptr, bnacc + 512, g2, b2, 1024, 256);
  gemm3<7, 64><<<dim3(512), dim3(256), 0, stream>>>(
      w2b, hb_t, bb2, nuf, xf1t, outp, nullptr, nuf, nuf, nuf, 256, 1024);
}

// Round 10
// 199.835 us; speedup vs baseline: 1.2818x; 1.0132x over previous
//
#include <hip/hip_runtime.h>
#include <hip/hip_bf16.h>
#include <cstdint>

// ---------------------------------------------------------------------------
// TextBlock: BN -> {q,k,v} -> MHSA (NH=16, KD=16, D=64, N=1024) -> proj -> +res
//            -> BN -> MLP(1024, relu6) -> +res.   B=8, C=256.
// I/O FLOAT32. Intermediates bf16 for MFMA, fp32 accumulation.
// R16 WIN: gemm gload_lds w16 + both-sides XOR swizzle.
// R19 WIN: attn K/V double-buffered gload_lds staging (76->44us).
// R20 WIN (202.5us): attn V-swizzle (row>>1)&3 basis (conflicts 2.1M->0,
//      time-neutral: not critical path) + gemm TM=128 modes 4/6 (-6us).
// R21: attn softmax denominator -> MFMA pipe. psum[n]=sum_m P[n][m] is a
//      mat-vec with ones: psacc[rg]=mfma(af,ones,psacc[rg]) (2 MFMA/tile on
//      the 22%-busy pipe) replaces 16 VALU adds/tile + epilogue shuffle+Ssum
//      LDS (VALUBusy 48% is the binding pipe). D2 layout: row=quad*4+reg =
//      exactly the epilogue's n indexing -> inv = 1/psacc[rg][j], no reduce.
//      Ones-B is m-permutation-invariant -> Pscr slot mapping untouched.
// R22: resubmit of R21 unchanged (R9 bench was an infra failure: container
//      acquisition, kernel never ran).
// ---------------------------------------------------------------------------

typedef __attribute__((ext_vector_type(8))) short short8;
typedef __attribute__((ext_vector_type(4))) float floatx4;

#define QK_SC 5.770780163555851f   // sqrt(kd)=4 times log2(e), folded into Q

__device__ __forceinline__ float b2f(unsigned short u) {
  union { unsigned int i; float f; } x; x.i = ((unsigned int)u) << 16; return x.f;
}
__device__ __forceinline__ unsigned short f2b(float f) {
  union { float f; unsigned int i; } x; x.f = f;
  unsigned int r = x.i + 0x7FFFu + ((x.i >> 16) & 1u);   // RNE
  return (unsigned short)(r >> 16);
}
// packed f32x2 -> bf16x2 (v_cvt_pk_bf16_f32 on gfx950)
__device__ __forceinline__ unsigned int f2b2(float a, float b) {
  __hip_bfloat162 h = __float22bfloat162_rn(make_float2(a, b));
  union { __hip_bfloat162 v; unsigned int u; } x; x.v = h; return x.u;
}
// async global->LDS, 16B per lane; LDS dest is wave-uniform base + lane*16.
__device__ __forceinline__ void gload16(const unsigned short* g, unsigned short* l) {
  __builtin_amdgcn_global_load_lds(
      (const __attribute__((address_space(1))) unsigned int*)g,
      (__attribute__((address_space(3))) unsigned int*)l, 16, 0, 0);
}

// ---------------------------------------------------------------------------
// prep: blocks 0..1151 convert the 6 weight mats f32->bf16 into wb;
//       blocks 1152..3199 accumulate BN1 partial sums of x into bnacc;
//       blocks 3200..3205 concat bq|bk|bv into biasqkv.
// ---------------------------------------------------------------------------
__global__ __launch_bounds__(256) void prep(
    const float* __restrict__ s0, const float* __restrict__ s1,
    const float* __restrict__ s2, const float* __restrict__ s3,
    const float* __restrict__ s4, const float* __restrict__ s5,
    unsigned short* __restrict__ dst,
    const float* __restrict__ x, float* __restrict__ acc,
    const float* __restrict__ bq, const float* __restrict__ bk,
    const float* __restrict__ bv, float* __restrict__ biasqkv) {
  int blk = blockIdx.x, t = threadIdx.x;
  if (blk < 1152) {
    int i = blk * 256 + t;   // float4-group index
    if (i >= 294912) return;
    const float* s; int li; size_t dbase;
    if (i < 16384)       { s = s0; li = i;          dbase = 0; }
    else if (i < 32768)  { s = s1; li = i - 16384;  dbase = 65536; }
    else if (i < 98304)  { s = s2; li = i - 32768;  dbase = 131072; }
    else if (i < 163840) { s = s3; li = i - 98304;  dbase = 393216; }
    else if (i < 229376) { s = s4; li = i - 163840; dbase = 655360; }
    else                 { s = s5; li = i - 229376; dbase = 917504; }
    float4 v = ((const float4*)s)[li];
    uint2 o; o.x = f2b2(v.x, v.y); o.y = f2b2(v.z, v.w);
    ((uint2*)(dst + dbase))[li] = o;
  } else if (blk < 3200) {
    int blk2 = blk - 1152;
    int b = blk2 >> 8, c = blk2 & 255;
    const float* p = x + (((size_t)(b * 256 + c)) << 10);
    float4 v = ((const float4*)p)[t];
    float s = (v.x + v.y) + (v.z + v.w);
    float s2 = (v.x * v.x + v.y * v.y) + (v.z * v.z + v.w * v.w);
    #pragma unroll
    for (int o = 32; o > 0; o >>= 1) { s += __shfl_down(s, o, 64); s2 += __shfl_down(s2, o, 64); }
    __shared__ float rs[4], rs2[4];
    int w = t >> 6;
    if ((t & 63) == 0) { rs[w] = s; rs2[w] = s2; }
    __syncthreads();
    if (t == 0) {
      atomicAdd(acc + c, (rs[0] + rs[1]) + (rs[2] + rs[3]));
      atomicAdd(acc + 256 + c, (rs2[0] + rs2[1]) + (rs2[2] + rs2[3]));
    }
  } else {
    int i = (blk - 3200) * 256 + t;   // 0..1535
    float v = (i < 256) ? bq[i] : (i < 512) ? bk[i - 256] : bv[i - 512];
    biasqkv[i] = v;
  }
}

// ---------------------------------------------------------------------------
// BN apply + transpose (finalize fused): x[b][c][n] f32 -> y_t[b][n][c] bf16.
// ---------------------------------------------------------------------------
__global__ __launch_bounds__(256) void bn_apply_t(
    const float* __restrict__ x, const float* __restrict__ acc,
    const float* __restrict__ g, const float* __restrict__ bb,
    unsigned short* __restrict__ yt) {
  int nt = blockIdx.x, ct = blockIdx.y, b = blockIdx.z;
  int t = threadIdx.x;
  __shared__ unsigned short T[64][72];
  {
    int r = t >> 2, g4 = (t & 3) * 16;
    int c = ct * 64 + r;
    float m = acc[c] * (1.0f / 8192.0f);
    float var = acc[256 + c] * (1.0f / 8192.0f) - m * m;
    float scl = g[c] * rsqrtf(var + 1e-5f);
    float shf = bb[c] - m * scl;
    const float* p = x + (((size_t)(b * 256 + c)) << 10) + nt * 64 + g4;
    float4 u0 = *(const float4*)(p);
    float4 u1 = *(const float4*)(p + 4);
    float4 u2 = *(const float4*)(p + 8);
    float4 u3 = *(const float4*)(p + 12);
    uint4 o0, o1;
    o0.x = f2b2(fmaf(u0.x, scl, shf), fmaf(u0.y, scl, shf));
    o0.y = f2b2(fmaf(u0.z, scl, shf), fmaf(u0.w, scl, shf));
    o0.z = f2b2(fmaf(u1.x, scl, shf), fmaf(u1.y, scl, shf));
    o0.w = f2b2(fmaf(u1.z, scl, shf), fmaf(u1.w, scl, shf));
    o1.x = f2b2(fmaf(u2.x, scl, shf), fmaf(u2.y, scl, shf));
    o1.y = f2b2(fmaf(u2.z, scl, shf), fmaf(u2.w, scl, shf));
    o1.z = f2b2(fmaf(u3.x, scl, shf), fmaf(u3.y, scl, shf));
    o1.w = f2b2(fmaf(u3.z, scl, shf), fmaf(u3.w, scl, shf));
    *(uint4*)&T[r][g4] = o0;
    *(uint4*)&T[r][g4 + 8] = o1;
  }
  __syncthreads();
  {
    int nr = t >> 2, cg = (t & 3) * 16;
    unsigned int ob[8];
    #pragma unroll
    for (int j = 0; j < 8; ++j) {
      unsigned int lo = T[cg + 2 * j][nr];
      unsigned int hi = T[cg + 2 * j + 1][nr];
      ob[j] = lo | (hi << 16);
    }
    unsigned short* orow = yt + ((size_t)(b * 1024 + nt * 64 + nr)) * 256 + ct * 64 + cg;
    *(uint4*)&orow[0] = make_uint4(ob[0], ob[1], ob[2], ob[3]);
    *(uint4*)&orow[8] = make_uint4(ob[4], ob[5], ob[6], ob[7]);
  }
}

// ---------------------------------------------------------------------------
// MFMA GEMM (TMx64 tile, BK=64, (256,4)):  out = W[M,K] @ Bn_b[N,K]^T + bias
// R16 staging: global_load_lds w16 into UNPADDED LDS, both-sides XOR swizzle
// ((cg ^ (row&7))<<4). TM=128 (modes 4,6): wave computes 32x64 (2 rowgroups),
// 16 MFMA / 12 ds_read. TM=64 (modes 5,7): wave computes 16x64 (proven R16).
// ---------------------------------------------------------------------------
template <int MODE, int TM>
__global__ __launch_bounds__(256, 4) void gemm3(
    const unsigned short* __restrict__ W, const unsigned short* __restrict__ Bn,
    const float* __restrict__ bias, const float* __restrict__ resf,
    const unsigned short* __restrict__ resb, void* __restrict__ outv,
    float* __restrict__ stats, const float* __restrict__ bnin,
    const float* __restrict__ g, const float* __restrict__ bb, int M, int K) {
  constexpr int RG = TM / 64;     // rowgroups per wave
  constexpr int WR = TM / 4;      // rows per wave
  int bid = blockIdx.x;
  int b = bid & 7;                 // XCD-grouped: each XCD owns one batch
  int rest = bid >> 3;
  int n0 = (rest & 15) * 64, m0 = (rest >> 4) * TM;
  int t = threadIdx.x, lane = t & 63, w = t >> 6;
  int ml = lane & 15, quad = lane >> 4;

  __shared__ unsigned short Wt[TM][64];
  __shared__ unsigned short Yt[64][64];
  __shared__ float Scl[256], Shf[256];

  if (MODE == 6) {   // precompute BN2 scale/shift (c = t)
    float m = bnin[t] * (1.0f / 8192.0f);
    float var = bnin[256 + t] * (1.0f / 8192.0f) - m * m;
    float scl = g[t] * rsqrtf(var + 1e-5f);
    Scl[t] = scl;
    Shf[t] = bb[t] - m * scl;
    __syncthreads();
  }

  const unsigned short* Bp = Bn + (size_t)b * 1024 * K;
  int sr = t >> 2, scg = (t & 3) * 16;                 // mode-6 B staging coords
  const unsigned short* brow = Bp + (size_t)(n0 + sr) * K + scg;

  // gload staging coords (per wave-call of 8 rows)
  int lrow = lane >> 3;                 // 0..7 within call
  int cgs  = (lane & 7) ^ lrow;         // pre-swizzled source col-group

  char* Wb = (char*)&Wt[0][0];
  char* Yb = (char*)&Yt[0][0];
  const int swa = (ml & 7) << 4;        // read-side XOR byte mask

  floatx4 acc[RG][4];
  #pragma unroll
  for (int rg = 0; rg < RG; ++rg)
    #pragma unroll
    for (int i = 0; i < 4; ++i) acc[rg][i] = (floatx4){0.f, 0.f, 0.f, 0.f};

  for (int k0 = 0; k0 < K; k0 += 64) {
    // --- stage W tile: WR/8 gload calls/wave (8 rows each) ---
    #pragma unroll
    for (int j = 0; j < WR / 8; ++j) {
      int row = w * WR + j * 8 + lrow;
      gload16(W + (size_t)(m0 + row) * K + k0 + cgs * 8, &Wt[w * WR + j * 8][0]);
    }
    if (MODE == 6) {   // BN2-apply inline: y2 = xf1*scl + shf -> swizzled store
      uint4 r0 = *(const uint4*)(brow + k0);
      uint4 r1 = *(const uint4*)(brow + k0 + 8);
      int cb = k0 + scg;
      float4 s0 = *(const float4*)&Scl[cb],     h0 = *(const float4*)&Shf[cb];
      float4 s1 = *(const float4*)&Scl[cb + 4], h1 = *(const float4*)&Shf[cb + 4];
      float4 s2 = *(const float4*)&Scl[cb + 8], h2 = *(const float4*)&Shf[cb + 8];
      float4 s3 = *(const float4*)&Scl[cb + 12], h3 = *(const float4*)&Shf[cb + 12];
      uint4 o0, o1;
      o0.x = f2b2(fmaf(b2f(r0.x & 0xffff), s0.x, h0.x), fmaf(b2f(r0.x >> 16), s0.y, h0.y));
      o0.y = f2b2(fmaf(b2f(r0.y & 0xffff), s0.z, h0.z), fmaf(b2f(r0.y >> 16), s0.w, h0.w));
      o0.z = f2b2(fmaf(b2f(r0.z & 0xffff), s1.x, h1.x), fmaf(b2f(r0.z >> 16), s1.y, h1.y));
      o0.w = f2b2(fmaf(b2f(r0.w & 0xffff), s1.z, h1.z), fmaf(b2f(r0.w >> 16), s1.w, h1.w));
      o1.x = f2b2(fmaf(b2f(r1.x & 0xffff), s2.x, h2.x), fmaf(b2f(r1.x >> 16), s2.y, h2.y));
      o1.y = f2b2(fmaf(b2f(r1.y & 0xffff), s2.z, h2.z), fmaf(b2f(r1.y >> 16), s2.w, h2.w));
      o1.z = f2b2(fmaf(b2f(r1.z & 0xffff), s3.x, h3.x), fmaf(b2f(r1.z >> 16), s3.y, h3.y));
      o1.w = f2b2(fmaf(b2f(r1.w & 0xffff), s3.z, h3.z), fmaf(b2f(r1.w >> 16), s3.w, h3.w));
      int sg0 = (t & 3) * 2, sg1 = sg0 + 1;           // logical 8-short groups
      *(uint4*)(Yb + sr * 128 + ((sg0 ^ (sr & 7)) << 4)) = o0;
      *(uint4*)(Yb + sr * 128 + ((sg1 ^ (sr & 7)) << 4)) = o1;
    } else {
      // --- stage B tile via gload, same pre-swizzle ---
      #pragma unroll
      for (int j = 0; j < 2; ++j) {
        int row = w * 16 + j * 8 + lrow;
        gload16(Bp + (size_t)(n0 + row) * K + k0 + cgs * 8, &Yt[w * 16 + j * 8][0]);
      }
    }
    __syncthreads();
    short8 a0[RG], a1[RG];
    #pragma unroll
    for (int rg = 0; rg < RG; ++rg) {
      int arow = w * WR + rg * 16 + ml;
      a0[rg] = *(const short8*)(Wb + arow * 128 + ((quad << 4) ^ swa));
      a1[rg] = *(const short8*)(Wb + arow * 128 + (((quad + 4) << 4) ^ swa));
    }
    #pragma unroll
    for (int nt2 = 0; nt2 < 4; ++nt2) {
      int brw = nt2 * 16 + ml;
      short8 b0 = *(const short8*)(Yb + brw * 128 + ((quad << 4) ^ swa));
      short8 b1 = *(const short8*)(Yb + brw * 128 + (((quad + 4) << 4) ^ swa));
      #pragma unroll
      for (int rg = 0; rg < RG; ++rg) {
        acc[rg][nt2] = __builtin_amdgcn_mfma_f32_16x16x32_bf16(a0[rg], b0, acc[rg][nt2], 0, 0, 0);
        acc[rg][nt2] = __builtin_amdgcn_mfma_f32_16x16x32_bf16(a1[rg], b1, acc[rg][nt2], 0, 0, 0);
      }
    }
    __syncthreads();
  }

  #pragma unroll
  for (int rg = 0; rg < RG; ++rg) {
    int row_base = m0 + w * WR + rg * 16 + quad * 4;

    if (MODE == 4) {
      int hh = row_base >> 4;       // 0..95
      float b0 = bias[row_base + 0], b1 = bias[row_base + 1];
      float b2 = bias[row_base + 2], b3 = bias[row_base + 3];
      if (hh < 32) {                // q (hh<16) or k
        unsigned short* qkout = (unsigned short*)outv + ((hh < 16) ? 0 : 2097152);
        float os = (hh < 16) ? QK_SC : 1.0f;
        int head = hh & 15, kd0 = row_base & 15;
        #pragma unroll
        for (int c = 0; c < 4; ++c) {
          int col = n0 + c * 16 + ml;
          uint2 pw;
          pw.x = f2b2((acc[rg][c][0] + b0) * os, (acc[rg][c][1] + b1) * os);
          pw.y = f2b2((acc[rg][c][2] + b2) * os, (acc[rg][c][3] + b3) * os);
          *(uint2*)&qkout[(((size_t)b * 16 + head) * 1024 + col) * 16 + kd0] = pw;
        }
      } else {                      // v: k-major [b][d][1024]
        unsigned short* vout = (unsigned short*)outv + 4194304;
        int d0 = row_base - 512;
        #pragma unroll
        for (int c = 0; c < 4; ++c) {
          int col = n0 + c * 16 + ml;
          vout[((size_t)b * 1024 + d0 + 0) * 1024 + col] = f2b(acc[rg][c][0] + b0);
          vout[((size_t)b * 1024 + d0 + 1) * 1024 + col] = f2b(acc[rg][c][1] + b1);
          vout[((size_t)b * 1024 + d0 + 2) * 1024 + col] = f2b(acc[rg][c][2] + b2);
          vout[((size_t)b * 1024 + d0 + 3) * 1024 + col] = f2b(acc[rg][c][3] + b3);
        }
      }
    } else if (MODE == 5) {          // proj -> xf1_t n-major bf16 + stats
      unsigned short* outp = (unsigned short*)outv;
      float vsum[4] = {0.f, 0.f, 0.f, 0.f}, vsq[4] = {0.f, 0.f, 0.f, 0.f};
      #pragma unroll
      for (int c = 0; c < 4; ++c) {
        int col = n0 + c * 16 + ml;
        float v0 = acc[rg][c][0] + bias[row_base + 0] + resf[((size_t)b * 256 + row_base + 0) * 1024 + col];
        float v1 = acc[rg][c][1] + bias[row_base + 1] + resf[((size_t)b * 256 + row_base + 1) * 1024 + col];
        float v2 = acc[rg][c][2] + bias[row_base + 2] + resf[((size_t)b * 256 + row_base + 2) * 1024 + col];
        float v3 = acc[rg][c][3] + bias[row_base + 3] + resf[((size_t)b * 256 + row_base + 3) * 1024 + col];
        vsum[0] += v0; vsq[0] += v0 * v0;
        vsum[1] += v1; vsq[1] += v1 * v1;
        vsum[2] += v2; vsq[2] += v2 * v2;
        vsum[3] += v3; vsq[3] += v3 * v3;
        uint2 pw; pw.x = f2b2(v0, v1); pw.y = f2b2(v2, v3);
        *(uint2*)&outp[((size_t)b * 1024 + col) * 256 + row_base] = pw;
      }
      #pragma unroll
      for (int r = 0; r < 4; ++r) {
        float s = vsum[r], q = vsq[r];
        #pragma unroll
        for (int o = 1; o < 16; o <<= 1) { s += __shfl_xor(s, o, 64); q += __shfl_xor(q, o, 64); }
        if (ml == 0) {
          atomicAdd(stats + row_base + r, s);
          atomicAdd(stats + 256 + row_base + r, q);
        }
      }
    } else if (MODE == 6) {          // MLP1 -> hb_t n-major bf16 + relu6
      unsigned short* outp = (unsigned short*)outv;
      #pragma unroll
      for (int c = 0; c < 4; ++c) {
        int col = n0 + c * 16 + ml;
        float v0 = fminf(fmaxf(acc[rg][c][0] + bias[row_base + 0], 0.f), 6.f);
        float v1 = fminf(fmaxf(acc[rg][c][1] + bias[row_base + 1], 0.f), 6.f);
        float v2 = fminf(fmaxf(acc[rg][c][2] + bias[row_base + 2], 0.f), 6.f);
        float v3 = fminf(fmaxf(acc[rg][c][3] + bias[row_base + 3], 0.f), 6.f);
        uint2 pw; pw.x = f2b2(v0, v1); pw.y = f2b2(v2, v3);
        *(uint2*)&outp[((size_t)b * 1024 + col) * 1024 + row_base] = pw;
      }
    } else {                          // MODE 7: MLP2 -> d_out f32 + res from xf1_t
      float* outp = (float*)outv;
      #pragma unroll
      for (int c = 0; c < 4; ++c) {
        int col = n0 + c * 16 + ml;
        uint2 rv = *(const uint2*)(resb + ((size_t)b * 1024 + col) * 256 + row_base);
        float r0 = b2f((unsigned short)(rv.x & 0xffff));
        float r1 = b2f((unsigned short)(rv.x >> 16));
        float r2 = b2f((unsigned short)(rv.y & 0xffff));
        float r3 = b2f((unsigned short)(rv.y >> 16));
        outp[((size_t)b * 256 + row_base + 0) * 1024 + col] = acc[rg][c][0] + bias[row_base + 0] + r0;
        outp[((size_t)b * 256 + row_base + 1) * 1024 + col] = acc[rg][c][1] + bias[row_base + 1] + r1;
        outp[((size_t)b * 256 + row_base + 2) * 1024 + col] = acc[rg][c][2] + bias[row_base + 2] + r2;
        outp[((size_t)b * 256 + row_base + 3) * 1024 + col] = acc[rg][c][3] + bias[row_base + 3] + r3;
      }
    }
  }
}

// ---------------------------------------------------------------------------
// Attention R19+R20a+R21: K/V double-buffered via global_load_lds; V swizzle
// (row>>1)&3 basis. Softmax denominator via ones-MFMA into psacc (no VALU
// adds, no shuffle reduce, no Ssum). One barrier/iter. 4 waves, (256,4).
// ---------------------------------------------------------------------------
__global__ __launch_bounds__(256, 4) void attn_kernel(
    const unsigned short* __restrict__ qt, const unsigned short* __restrict__ kt,
    const unsigned short* __restrict__ vt, unsigned short* __restrict__ ot) {
  int bx0 = blockIdx.x;
  int bx = (bx0 & 7) * 128 + (bx0 >> 3);   // bijective XCD grouping
  int nt = bx & 7, h = (bx >> 3) & 15, b = bx >> 7;
  int tid = threadIdx.x, lane = tid & 63, w = tid >> 6;
  int ml = lane & 15, quad = lane >> 4;

  __shared__ unsigned int Pscr[4][2][2][16][18];  // [wave][buf][rg][n][m-packed u32]
  __shared__ unsigned short Kt[2][32][16];        // 2x1KB, linear
  __shared__ unsigned short Vt[2][64][32];        // 2x4KB, swizzled cols

  const int n0 = nt * 128 + w * 32;
  const size_t qk_row = ((size_t)b * 16 + h) * 1024;

  short8 qf[2];
  #pragma unroll
  for (int rg = 0; rg < 2; ++rg) {
    short8 z = {0, 0, 0, 0, 0, 0, 0, 0};
    if (quad < 2)
      z = *(const short8*)(qt + (qk_row + n0 + rg * 16 + ml) * 16 + quad * 8);
    qf[rg] = z;
  }

  // ones fragment (bf16 1.0 = 0x3F80) for the denominator MFMA
  const short one_bf = (short)0x3F80;
  const short8 onesf = {one_bf, one_bf, one_bf, one_bf, one_bf, one_bf, one_bf, one_bf};

  const floatx4 zf = {0.f, 0.f, 0.f, 0.f};
  floatx4 oacc[2][4];
  floatx4 psacc[2];
  #pragma unroll
  for (int rg = 0; rg < 2; ++rg) {
    psacc[rg] = zf;
    #pragma unroll
    for (int dt = 0; dt < 4; ++dt) oacc[rg][dt] = zf;
  }

  const unsigned short* kp = kt + qk_row * 16;
  const unsigned short* vp = vt + ((size_t)b * 1024 + h * 64) * 1024;

  // staging coords (V): wave w covers rows w*16..w*16+15 of the 64-row tile.
  // Swizzle basis (row>>1)&3: source cg = (l&3) ^ ((l>>3)&3).
  int vrow = w * 16 + (lane >> 2);           // per-lane V row (0..63)
  int vcg  = (lane & 3) ^ ((lane >> 3) & 3); // pre-swizzled source col-group

  auto stageKV = [&](int buf, int mc) {
    gload16(vp + (size_t)vrow * 1024 + mc + vcg * 8, &Vt[buf][w * 16][0]);
    if (w == 0)
      gload16(kp + (size_t)mc * 16 + lane * 8, &Kt[buf][0][0]);
  };

  // prologue: tile 0 staged
  stageKV(0, 0);
  __syncthreads();

  for (int it = 0; it < 32; ++it) {
    int buf = it & 1;
    int mc = it << 5;
    if (it < 31) stageKV(buf ^ 1, mc + 32);   // prefetch next tile

    // --- read K frags from LDS (linear; quad>=2 lanes are zero / K=16) ---
    const char* Kb = (const char*)&Kt[buf][0][0];
    const char* Vb = (const char*)&Vt[buf][0][0];
    const short8 z8 = {0, 0, 0, 0, 0, 0, 0, 0};
    short8 kf[2];
    #pragma unroll
    for (int tt = 0; tt < 2; ++tt)
      kf[tt] = (quad < 2) ? *(const short8*)(Kb + (tt * 16 + ml) * 32 + quad * 16) : z8;
    // --- read V frags (XOR-swizzled cols, (row>>1)&3 basis) ---
    short8 vf[4];
    #pragma unroll
    for (int dt = 0; dt < 4; ++dt)
      vf[dt] = *(const short8*)(Vb + (dt * 16 + ml) * 64 + ((quad ^ ((ml >> 1) & 3)) << 4));

    #pragma unroll
    for (int rg = 0; rg < 2; ++rg) {
      #pragma unroll
      for (int tt = 0; tt < 2; ++tt) {
        floatx4 s = __builtin_amdgcn_mfma_f32_16x16x32_bf16(kf[tt], qf[rg], zf, 0, 0, 0);
        float p0 = __builtin_amdgcn_exp2f(s[0]);
        float p1 = __builtin_amdgcn_exp2f(s[1]);
        float p2 = __builtin_amdgcn_exp2f(s[2]);
        float p3 = __builtin_amdgcn_exp2f(s[3]);
        uint2 pw; pw.x = f2b2(p0, p1); pw.y = f2b2(p2, p3);
        *(uint2*)&Pscr[w][buf][rg][ml][tt * 8 + quad * 2] = pw;
      }
    }
    #pragma unroll
    for (int rg = 0; rg < 2; ++rg) {
      uint2 a0 = *(const uint2*)&Pscr[w][buf][rg][ml][quad * 4];
      uint2 a1 = *(const uint2*)&Pscr[w][buf][rg][ml][quad * 4 + 2];
      union { uint4 u; short8 s; } cv;
      cv.u = make_uint4(a0.x, a0.y, a1.x, a1.y);
      short8 af = cv.s;
      psacc[rg] = __builtin_amdgcn_mfma_f32_16x16x32_bf16(af, onesf, psacc[rg], 0, 0, 0);
      #pragma unroll
      for (int dt = 0; dt < 4; ++dt)
        oacc[rg][dt] = __builtin_amdgcn_mfma_f32_16x16x32_bf16(af, vf[dt], oacc[rg][dt], 0, 0, 0);
    }
    __syncthreads();   // drains prefetch (vmcnt) + protects buf reuse
  }

  #pragma unroll
  for (int rg = 0; rg < 2; ++rg) {
    float inv0 = 1.0f / psacc[rg][0], inv1 = 1.0f / psacc[rg][1];
    float inv2 = 1.0f / psacc[rg][2], inv3 = 1.0f / psacc[rg][3];
    int nbase = n0 + rg * 16 + quad * 4;
    #pragma unroll
    for (int dt = 0; dt < 4; ++dt) {
      int dg = h * 64 + dt * 16 + ml;
      size_t obase = (((size_t)b << 10) + nbase) * 1024 + dg;
      ot[obase + 0 * 1024] = f2b(oacc[rg][dt][0] * inv0);
      ot[obase + 1 * 1024] = f2b(oacc[rg][dt][1] * inv1);
      ot[obase + 2 * 1024] = f2b(oacc[rg][dt][2] * inv2);
      ot[obase + 3 * 1024] = f2b(oacc[rg][dt][3] * inv3);
    }
  }
}

// ---------------------------------------------------------------------------
extern "C" void kernel_launch(void* const* d_in, const int* in_sizes, int n_in,
                              void* d_out, int out_size, void* d_ws, size_t ws_size,
                              hipStream_t stream) {
  const float* x   = (const float*)d_in[0];
  const float* g1  = (const float*)d_in[1];
  const float* b1  = (const float*)d_in[2];
  const float* wq  = (const float*)d_in[3];
  const float* bq  = (const float*)d_in[4];
  const float* wk  = (const float*)d_in[5];
  const float* bk  = (const float*)d_in[6];
  const float* wv  = (const float*)d_in[7];
  const float* bv  = (const float*)d_in[8];
  const float* wp  = (const float*)d_in[9];
  const float* bp  = (const float*)d_in[10];
  const float* g2  = (const float*)d_in[11];
  const float* b2  = (const float*)d_in[12];
  const float* w1  = (const float*)d_in[13];
  const float* bb1 = (const float*)d_in[14];
  const float* w2  = (const float*)d_in[15];
  const float* bb2 = (const float*)d_in[16];

  char* ws = (char*)d_ws;
  float* bnacc   = (float*)ws;                  // 1024 f: sum1,sq1 | sum2,sq2
  float* biasqkv = (float*)(ws + 4096);         // 1536 f
  unsigned short* y_t  = (unsigned short*)(ws + 16384);    // bf16 [8][1024][256]
  unsigned short* qt   = y_t + (size_t)2 * 1024 * 1024;    // bf16 [8][16][1024][16]
  unsigned short* kt   = qt  + (size_t)2 * 1024 * 1024;    // = qt + 2097152
  unsigned short* vt   = kt  + (size_t)2 * 1024 * 1024;    // = qt + 4194304
  unsigned short* ot   = vt  + (size_t)8 * 1024 * 1024;    // bf16 [8][1024][1024] n-major
  unsigned short* xf1t = ot  + (size_t)8 * 1024 * 1024;    // bf16 [8][1024][256] n-major
  unsigned short* wb   = xf1t + (size_t)2 * 1024 * 1024;
  unsigned short* hb_t = ot;          // reuse: ot dead after proj
  float* outp = (float*)d_out;

  unsigned short* wqkvb = wb;         // rows 0..255 wq | 256..511 wk | 512..1535 wv
  unsigned short* wpb = wb + 393216;
  unsigned short* w1b = wb + 655360;
  unsigned short* w2b = wb + 917504;
  const unsigned short* nub = nullptr;
  const float* nuf = nullptr;

  hipMemsetAsync(bnacc, 0, 4096, stream);
  prep<<<dim3(3206), dim3(256), 0, stream>>>(
      wq, wk, wv, wp, w1, w2, wb, x, bnacc, bq, bk, bv, biasqkv);

  // --- attention branch ---
  bn_apply_t<<<dim3(16, 4, 8), dim3(256), 0, stream>>>(x, bnacc, g1, b1, y_t);
  gemm3<4, 128><<<dim3(1536), dim3(256), 0, stream>>>(
      wqkvb, y_t, biasqkv, nuf, nub, qt, nullptr, nuf, nuf, nuf, 1536, 256);
  attn_kernel<<<dim3(1024), dim3(256), 0, stream>>>(qt, kt, vt, ot);
  gemm3<5, 64><<<dim3(512), dim3(256), 0, stream>>>(
      wpb, ot, bp, x, nub, xf1t, bnacc + 512, nuf, nuf, nuf, 256, 1024);

  // --- MLP branch ---
  gemm3<6, 128><<<dim3(1024), dim3(256), 0, stream>>>(
      w1b, xf1t, bb1, nuf, nub, hb_t, nullptr, bnacc + 512, g2, b2, 1024, 256);
  gemm3<7, 64><<<dim3(512), dim3(256), 0, stream>>>(
      w2b, hb_t, bb2, nuf, xf1t, outp, nullptr, nuf, nuf, nuf, 256, 1024);
}